// Round 8
// baseline (3718.724 us; speedup 1.0000x reference)
//
#include <hip/hip_runtime.h>

typedef __attribute__((ext_vector_type(8))) short bf16x8;
typedef __attribute__((ext_vector_type(4))) float f32x4;
typedef __attribute__((ext_vector_type(4))) int   i32x4;

#define T_LEN 512
#define BATCH 128
#define HID   256
#define G4    1024
#define WPI8_STRIDE 262144   // bytes per dir-layer: 64 tiles * 4 kk * 64 lanes * 16

__device__ __forceinline__ float sigmf(float x){
  return __builtin_amdgcn_rcpf(1.0f + __expf(-x));
}
__device__ __forceinline__ float tanhf_(float x){
  return 1.0f - 2.0f*__builtin_amdgcn_rcpf(1.0f + __expf(2.0f*x));
}
__device__ __forceinline__ unsigned short f2bf(float f){
  union{float f;unsigned u;} v; v.f=f;
  unsigned r = v.u + 0x7FFF + ((v.u>>16)&1);
  return (unsigned short)(r>>16);
}
__device__ __forceinline__ float bf2f(unsigned short b){
  union{unsigned u;float f;} v; v.u = ((unsigned)b)<<16; return v.f;
}

// ---- per-column scales for i8 quantization ----
// comb[dl][n] = max_k|w[n][k]| / 127^2 (acc->gate product scale), s_inv = 127/max
__global__ void k_scales(const float* __restrict__ w_hh0, const float* __restrict__ w_hh1,
                         float* __restrict__ comb, float* __restrict__ s_inv){
  int idx = blockIdx.x*256 + threadIdx.x;
  if (idx >= 3*1024) return;
  int dl = idx >> 10, n = idx & 1023;
  const float* src = (dl < 2) ? (w_hh0 + ((size_t)dl*1024 + n)*256)
                              : (w_hh1 + (size_t)n*256);
  float m = 1e-20f;
  for (int k = 0; k < 256; k += 4){
    float4 v = *(const float4*)&src[k];
    m = fmaxf(m, fmaxf(fmaxf(fabsf(v.x), fabsf(v.y)), fmaxf(fabsf(v.z), fabsf(v.w))));
  }
  s_inv[idx] = 127.f / m;
  comb[idx]  = m / 16129.f;
}

// ---- pack w_hh into i8 B-fragment order ----
// wp[dl][tile:64][kk:4][lane:64][j:16] ; tile = s*4+g
// B[k][n]: n = g*256 + s*16 + (lane&15), k = kk*64 + (lane>>4)*16 + j
__global__ void k_pack_i8(const float* __restrict__ w_hh0, const float* __restrict__ w_hh1,
                          const float* __restrict__ s_inv, char* __restrict__ wp){
  int idx = blockIdx.x*256 + threadIdx.x;
  if (idx >= 3*WPI8_STRIDE) return;
  int j    = idx & 15;
  int lane = (idx >> 4) & 63;
  int kk   = (idx >> 10) & 3;
  int tile = (idx >> 12) & 63;
  int dl   = idx >> 18;
  int g = tile & 3, s = tile >> 2;
  int n = g*256 + s*16 + (lane & 15);
  int k = kk*64 + ((lane >> 4) << 4) + j;
  const float* src = (dl < 2) ? (w_hh0 + ((size_t)dl*1024 + n)*256)
                              : (w_hh1 + (size_t)n*256);
  float v = src[k] * s_inv[dl*1024 + n];
  int q = (int)rintf(fminf(127.f, fmaxf(-127.f, v)));
  wp[idx] = (char)q;
}

__global__ void k_pack_wih1(const float* __restrict__ w, unsigned short* __restrict__ o, int n){
  int idx = blockIdx.x*256 + threadIdx.x;
  if (idx < n) o[idx] = f2bf(w[idx]);
}

// ---- full-width single-CU recurrence, i8 weights entirely register-resident ----
// MODE 0: layer0, 16 blocks (dir x bgrp). MODE 1: layer1 fwd, 8 blocks.
// 512 threads = 8 waves (2/SIMD). Wave w owns slices 2w,2w+1 (all 4 gates).
// No cross-block exchange: h lives in 8KB swizzled LDS, 1 barrier/step.
template<int MODE>
__global__ __launch_bounds__(512, 2) void k_rec8(
    const float* __restrict__ x,
    const char* __restrict__ wpack,
    const float* __restrict__ comb,
    const float* __restrict__ w_ih0,    // MODE0 [2][1024][4]
    const float* __restrict__ b0,       // MODE0 [2][1024]
    const unsigned short* __restrict__ xp, // MODE1 frag-packed gates
    unsigned short* __restrict__ y0,
    float* __restrict__ hS)
{
  const int tid  = threadIdx.x;
  const int lane = tid & 63;
  const int w    = tid >> 6;            // 0..7
  int dir, bgrp, dl;
  if (MODE == 0){ dir = blockIdx.x >> 3; bgrp = blockIdx.x & 7; dl = dir; }
  else          { dir = 0; bgrp = blockIdx.x; dl = 2; }
  const int b0r = bgrp * 16;

  __shared__ __align__(16) char  A_lds[2][16*256];  // h in i8, chunk-XOR swizzled
  __shared__ __align__(16) float x_lds[2][16][4];   // MODE0 x stage

  // ---- all w_hh weights into registers (256KB/block = 128 VGPR/wave) ----
  const i32x4* wpb = (const i32x4*)(wpack + (size_t)dl*WPI8_STRIDE);
  i32x4 breg[2][4][4];
  #pragma unroll
  for (int p = 0; p < 2; ++p)
    #pragma unroll
    for (int g = 0; g < 4; ++g)
      #pragma unroll
      for (int kk = 0; kk < 4; ++kk)
        breg[p][g][kk] = wpb[(((((2*w+p)*4 + g)*4) + kk) << 6) + lane];

  const int c   = lane & 15;            // A-frag row AND elementwise h-col offset
  const int rb  = (lane >> 4) << 2;     // batch-row base
  const int odd = lane & 1;

  float cmb[2][4];
  #pragma unroll
  for (int p = 0; p < 2; ++p)
    #pragma unroll
    for (int g = 0; g < 4; ++g)
      cmb[p][g] = comb[dl*1024 + g*256 + (2*w+p)*16 + c];

  unsigned wihpk[2][4][2]; float bia[2][4];
  if (MODE == 0){
    #pragma unroll
    for (int p = 0; p < 2; ++p)
      #pragma unroll
      for (int g = 0; g < 4; ++g){
        int col = g*256 + (2*w+p)*16 + c;
        const float* wr = &w_ih0[(size_t)(dir*1024 + col)*4];
        wihpk[p][g][0] = (unsigned)f2bf(wr[0]) | ((unsigned)f2bf(wr[1]) << 16);
        wihpk[p][g][1] = (unsigned)f2bf(wr[2]) | ((unsigned)f2bf(wr[3]) << 16);
        bia[p][g] = b0[dir*1024 + col];
      }
  }

  for (int i = tid; i < 16*256; i += 512) A_lds[0][i] = 0;   // h(0) = 0
  if (MODE == 0 && tid < 64){
    int row = tid >> 2, i = tid & 3;
    int t0 = dir ? (T_LEN-1) : 0;
    x_lds[0][row][i] = x[((size_t)(b0r+row)*T_LEN + t0)*4 + i];
  }

  float c_reg[2][4];
  #pragma unroll
  for (int p = 0; p < 2; ++p)
    #pragma unroll
    for (int r = 0; r < 4; ++r) c_reg[p][r] = 0.f;

  for (int tt = 0; tt < T_LEN; ++tt){
    const int t = (MODE == 0 && dir) ? (T_LEN-1-tt) : tt;
    const char* Ac = A_lds[tt & 1];
    char* An = (char*)A_lds[(tt + 1) & 1];

    __syncthreads();   // h(tt)/x(tt) complete in Ac

    // MODE1: C-in gate loads (consumed at elementwise; latency hides under MFMA)
    uint2 cin[2][4];
    if (MODE == 1){
      #pragma unroll
      for (int p = 0; p < 2; ++p)
        #pragma unroll
        for (int g = 0; g < 4; ++g)
          cin[p][g] = *(const uint2*)&xp[((((size_t)t*8 + bgrp)*16 + (2*w+p))*4 + g)*256 + c*16 + rb];
    }

    // A fragments (h i8), swizzle-read
    i32x4 a[4];
    #pragma unroll
    for (int kk = 0; kk < 4; ++kk)
      a[kk] = *(const i32x4*)&Ac[(c << 8) + ((((kk << 2) + (lane >> 4)) ^ c) << 4)];

    // MFMA: all B from registers
    i32x4 acc[2][4];
    #pragma unroll
    for (int p = 0; p < 2; ++p)
      #pragma unroll
      for (int g = 0; g < 4; ++g){
        acc[p][g] = (i32x4){0,0,0,0};
        #pragma unroll
        for (int kk = 0; kk < 4; ++kk)
          acc[p][g] = __builtin_amdgcn_mfma_i32_16x16x64_i8(a[kk], breg[p][g][kk], acc[p][g], 0, 0, 0);
      }

    float4 xr[4];
    if (MODE == 0){
      #pragma unroll
      for (int r = 0; r < 4; ++r)
        xr[r] = *(const float4*)&x_lds[tt & 1][rb + r][0];
    }

    // ---- elementwise: dequant + x-term/cin + LSTM cell + h re-quant ----
    #pragma unroll
    for (int p = 0; p < 2; ++p){
      const int jc = (2*w+p)*16 + c;
      float wv[4][4];
      if (MODE == 0){
        #pragma unroll
        for (int g = 0; g < 4; ++g){
          wv[g][0] = bf2f((unsigned short)(wihpk[p][g][0] & 0xFFFF));
          wv[g][1] = bf2f((unsigned short)(wihpk[p][g][0] >> 16));
          wv[g][2] = bf2f((unsigned short)(wihpk[p][g][1] & 0xFFFF));
          wv[g][3] = bf2f((unsigned short)(wihpk[p][g][1] >> 16));
        }
      }
      unsigned short hb[4];
      #pragma unroll
      for (int r = 0; r < 4; ++r){
        float gv[4];
        #pragma unroll
        for (int g = 0; g < 4; ++g){
          gv[g] = (float)acc[p][g][r] * cmb[p][g];
          if (MODE == 0){
            gv[g] += bia[p][g] + xr[r].x*wv[g][0] + xr[r].y*wv[g][1]
                               + xr[r].z*wv[g][2] + xr[r].w*wv[g][3];
          } else {
            unsigned uu = (r < 2) ? cin[p][g].x : cin[p][g].y;
            gv[g] += bf2f((unsigned short)((r & 1) ? (uu >> 16) : (uu & 0xFFFF)));
          }
        }
        float cc = sigmf(gv[1])*c_reg[p][r] + sigmf(gv[0])*tanhf_(gv[2]);
        c_reg[p][r] = cc;
        float h = sigmf(gv[3])*tanhf_(cc);
        hb[r] = f2bf(h);
        int row = rb + r;
        int hq = __float2int_rn(fminf(127.f, fmaxf(-127.f, h*127.f)));
        An[(row << 8) + ((((jc >> 4) ^ row)) << 4) + (jc & 15)] = (char)hq;
        if (MODE == 1 && tt == T_LEN-1)
          hS[(size_t)(b0r + row)*HID + jc] = h;
      }
      if (MODE == 0){
        // u32-pack via lane-pair exchange, write y0 bf16
        unsigned pk0 = (unsigned)hb[0] | ((unsigned)hb[1] << 16);
        unsigned pk1 = (unsigned)hb[2] | ((unsigned)hb[3] << 16);
        unsigned nb0 = (unsigned)__shfl_xor((int)pk0, 1, 64);
        unsigned nb1 = (unsigned)__shfl_xor((int)pk1, 1, 64);
        unsigned s0v = odd ? ((nb1 & 0xFFFFu) | (pk1 << 16))
                           : ((pk0 & 0xFFFFu) | (nb0 << 16));
        unsigned s1v = odd ? ((nb1 >> 16) | (pk1 & 0xFFFF0000u))
                           : ((pk0 >> 16) | (nb0 & 0xFFFF0000u));
        int r0 = rb + (odd ? 2 : 0);
        int colu = jc & ~1;
        *(unsigned*)&y0[((size_t)t*BATCH + (b0r + r0    ))*(2*HID) + dir*HID + colu] = s0v;
        *(unsigned*)&y0[((size_t)t*BATCH + (b0r + r0 + 1))*(2*HID) + dir*HID + colu] = s1v;
      }
    }

    if (MODE == 0 && tid < 64){   // stage x(next) into the other buffer
      int tn = dir ? (t > 0 ? t-1 : 0) : (t < T_LEN-1 ? t+1 : t);
      int row = tid >> 2, i = tid & 3;
      x_lds[(tt + 1) & 1][row][i] = x[((size_t)(b0r+row)*T_LEN + tn)*4 + i];
    }
  }
}

// ---- bf16 MFMA GEMM: C[M][1024] = A[M][512] * B[1024][512]^T + bias ----
// PLAIN=0: frag-packed bf16 out [t][bgrp:8][s:16][g:4][c:16][r:16]; PLAIN=1: fp32 [M][1024]
template<int PLAIN>
__global__ __launch_bounds__(256) void k_gemm_bf(
    const unsigned short* __restrict__ A, const unsigned short* __restrict__ B,
    const float* __restrict__ bias, unsigned short* __restrict__ outF, float* __restrict__ outP)
{
  __shared__ __align__(16) unsigned short As[128*64];
  __shared__ __align__(16) unsigned short Bs[128*64];
  const int tid  = threadIdx.x;
  const int lane = tid & 63;
  const int w = tid >> 6, wm = w >> 1, wn = w & 1;
  const int t  = blockIdx.y;
  const int n0 = blockIdx.x * 128;

  f32x4 acc[4][4];
  #pragma unroll
  for (int i = 0; i < 4; ++i)
    #pragma unroll
    for (int jx = 0; jx < 4; ++jx) acc[i][jx] = (f32x4){0.f,0.f,0.f,0.f};

  const int sr = tid >> 3;
  const int sq = tid & 7;

  for (int k0 = 0; k0 < 512; k0 += 64){
    #pragma unroll
    for (int it = 0; it < 4; ++it){
      int r = sr + it*32;
      uint4 av = *(const uint4*)&A[((size_t)t*128 + r)*512 + k0 + sq*8];
      uint4 bv = *(const uint4*)&B[((size_t)(n0 + r))*512 + k0 + sq*8];
      *(uint4*)&As[r*64 + (sq ^ (r & 7))*8] = av;
      *(uint4*)&Bs[r*64 + (sq ^ (r & 7))*8] = bv;
    }
    __syncthreads();
    bf16x8 af[4][2], bfv[4][2];
    #pragma unroll
    for (int mt = 0; mt < 4; ++mt)
      #pragma unroll
      for (int kk = 0; kk < 2; ++kk){
        int row = wm*64 + mt*16 + (lane & 15);
        af[mt][kk] = *(const bf16x8*)&As[row*64 + ((kk*4 + (lane>>4)) ^ (row & 7))*8];
      }
    #pragma unroll
    for (int nl = 0; nl < 4; ++nl)
      #pragma unroll
      for (int kk = 0; kk < 2; ++kk){
        int row = wn*64 + nl*16 + (lane & 15);
        bfv[nl][kk] = *(const bf16x8*)&Bs[row*64 + ((kk*4 + (lane>>4)) ^ (row & 7))*8];
      }
    #pragma unroll
    for (int mt = 0; mt < 4; ++mt)
      #pragma unroll
      for (int nl = 0; nl < 4; ++nl){
        acc[mt][nl] = __builtin_amdgcn_mfma_f32_16x16x32_bf16(af[mt][0], bfv[nl][0], acc[mt][nl], 0,0,0);
        acc[mt][nl] = __builtin_amdgcn_mfma_f32_16x16x32_bf16(af[mt][1], bfv[nl][1], acc[mt][nl], 0,0,0);
      }
    __syncthreads();
  }

  #pragma unroll
  for (int mt = 0; mt < 4; ++mt){
    #pragma unroll
    for (int nl = 0; nl < 4; ++nl){
      int ng = n0 + wn*64 + nl*16 + (lane & 15);
      float bv = bias[ng];
      f32x4 v = acc[mt][nl];
      if (PLAIN){
        int mrow = wm*64 + mt*16 + (lane >> 4)*4;
        #pragma unroll
        for (int r = 0; r < 4; ++r)
          outP[((size_t)t*128 + mrow + r)*G4 + ng] = v[r] + bv;
      } else {
        int bgrp = wm*4 + mt;
        int s  = (ng >> 4) & 15;
        int g  = ng >> 8;
        int cg = ng & 15;
        unsigned short hb[4];
        #pragma unroll
        for (int r = 0; r < 4; ++r) hb[r] = f2bf(v[r] + bv);
        *(uint2*)&outF[((((size_t)t*8 + bgrp)*16 + s)*4 + g)*256 + cg*16 + ((lane >> 4) << 2)] = *(uint2*)hb;
      }
    }
  }
}

// ---- final: layer-1 bwd single step + combine + out proj + softmax ----
__global__ __launch_bounds__(256) void k_final(const float* __restrict__ hS,
                                               const float* __restrict__ xp1b,
                                               const float* __restrict__ w_out,
                                               const float* __restrict__ b_out,
                                               float* __restrict__ out)
{
  const int b = blockIdx.x, j = threadIdx.x;
  float iv = xp1b[b*G4 + 0*HID + j];
  float gv = xp1b[b*G4 + 2*HID + j];
  float ov = xp1b[b*G4 + 3*HID + j];
  float c  = sigmf(iv)*tanhf_(gv);
  float hb = sigmf(ov)*tanhf_(c);
  float last = hS[b*HID + j] + hb;

  __shared__ float part[3][256];
  part[0][j] = last * w_out[0*HID + j];
  part[1][j] = last * w_out[1*HID + j];
  part[2][j] = last * w_out[2*HID + j];
  __syncthreads();
  for (int s = 128; s > 0; s >>= 1){
    if (j < s){
      part[0][j] += part[0][j+s];
      part[1][j] += part[1][j+s];
      part[2][j] += part[2][j+s];
    }
    __syncthreads();
  }
  if (j == 0){
    float l0 = part[0][0] + b_out[0];
    float l1 = part[1][0] + b_out[1];
    float l2 = part[2][0] + b_out[2];
    float m = fmaxf(l0, fmaxf(l1, l2));
    float e0 = __expf(l0-m), e1 = __expf(l1-m), e2 = __expf(l2-m);
    float s = e0 + e1 + e2;
    out[b*3+0] = e0/s; out[b*3+1] = e1/s; out[b*3+2] = e2/s;
  }
}

extern "C" void kernel_launch(void* const* d_in, const int* in_sizes, int n_in,
                              void* d_out, int out_size, void* d_ws, size_t ws_size,
                              hipStream_t stream) {
  const float* x     = (const float*)d_in[0];
  const float* w_ih0 = (const float*)d_in[1];
  const float* w_hh0 = (const float*)d_in[2];
  const float* b0p   = (const float*)d_in[3];
  const float* w_ih1 = (const float*)d_in[4];
  const float* w_hh1 = (const float*)d_in[5];
  const float* b1p   = (const float*)d_in[6];
  const float* w_out = (const float*)d_in[7];
  const float* b_out = (const float*)d_in[8];
  float* out = (float*)d_out;

  // workspace layout
  unsigned short* y0    = (unsigned short*)d_ws;                 // 33,554,432 u16
  unsigned short* xp1   = y0    + (size_t)T_LEN*BATCH*2*HID;     // 67,108,864 u16
  unsigned short* wih1p = xp1   + (size_t)T_LEN*BATCH*G4;        // 1,048,576 u16
  float*          comb  = (float*)(wih1p + 2*G4*2*HID);          // 3072 f32
  float*          s_inv = comb  + 3*1024;                        // 3072 f32
  float*          xp1b  = s_inv + 3*1024;                        // 131,072 f32
  float*          hS    = xp1b  + BATCH*G4;                      // 32,768 f32
  char*           wpi8  = (char*)(hS + BATCH*HID);               // 786,432 B

  // weight prep
  k_scales<<<12, 256, 0, stream>>>(w_hh0, w_hh1, comb, s_inv);
  k_pack_i8<<<3072, 256, 0, stream>>>(w_hh0, w_hh1, s_inv, wpi8);
  k_pack_wih1<<<4096, 256, 0, stream>>>(w_ih1, wih1p, 2*G4*2*HID);

  // layer 0, both directions: full-width single-CU blocks, no exchange
  k_rec8<0><<<16, 512, 0, stream>>>(x, wpi8, comb, w_ih0, b0p, nullptr, y0, nullptr);

  // layer-1 input projection (fwd dir), frag-packed bf16 out
  k_gemm_bf<0><<<dim3(8, 512), 256, 0, stream>>>(y0, wih1p, b1p, xp1, nullptr);

  // layer-1 backward first step gates: plain fp32
  k_gemm_bf<1><<<dim3(8, 1), 256, 0, stream>>>(y0 + (size_t)(T_LEN-1)*BATCH*2*HID,
                                               wih1p + (size_t)G4*2*HID, b1p + G4,
                                               nullptr, xp1b);

  // layer 1 forward recurrence
  k_rec8<1><<<8, 512, 0, stream>>>(nullptr, wpi8, comb, nullptr, nullptr, xp1, nullptr, hS);

  k_final<<<BATCH, 256, 0, stream>>>(hS, xp1b, w_out, b_out, out);
}

// Round 9
// 2695.617 us; speedup vs baseline: 1.3795x; 1.3795x over previous
//
#include <hip/hip_runtime.h>

typedef __attribute__((ext_vector_type(8))) short bf16x8;
typedef __attribute__((ext_vector_type(4))) float f32x4;
typedef __attribute__((ext_vector_type(4))) int   i32x4;

#define T_LEN 512
#define BATCH 128
#define HID   256
#define G4    1024
#define WPI8_STRIDE 262144   // bytes per dir-layer: 64 tiles * 4 kk * 64 lanes * 16

__device__ __forceinline__ float sigmf(float x){
  return __builtin_amdgcn_rcpf(1.0f + __expf(-x));
}
__device__ __forceinline__ float tanhf_(float x){
  return 1.0f - 2.0f*__builtin_amdgcn_rcpf(1.0f + __expf(2.0f*x));
}
__device__ __forceinline__ unsigned short f2bf(float f){
  union{float f;unsigned u;} v; v.f=f;
  unsigned r = v.u + 0x7FFF + ((v.u>>16)&1);
  return (unsigned short)(r>>16);
}
__device__ __forceinline__ float bf2f(unsigned short b){
  union{unsigned u;float f;} v; v.u = ((unsigned)b)<<16; return v.f;
}

// ---- per-column scales for i8 quantization ----
__global__ void k_scales(const float* __restrict__ w_hh0, const float* __restrict__ w_hh1,
                         float* __restrict__ comb, float* __restrict__ s_inv){
  int idx = blockIdx.x*256 + threadIdx.x;
  if (idx >= 3*1024) return;
  int dl = idx >> 10, n = idx & 1023;
  const float* src = (dl < 2) ? (w_hh0 + ((size_t)dl*1024 + n)*256)
                              : (w_hh1 + (size_t)n*256);
  float m = 1e-20f;
  for (int k = 0; k < 256; k += 4){
    float4 v = *(const float4*)&src[k];
    m = fmaxf(m, fmaxf(fmaxf(fabsf(v.x), fabsf(v.y)), fmaxf(fabsf(v.z), fabsf(v.w))));
  }
  s_inv[idx] = 127.f / m;
  comb[idx]  = m / 16129.f;
}

// ---- pack w_hh into i8 B-fragment order ----
__global__ void k_pack_i8(const float* __restrict__ w_hh0, const float* __restrict__ w_hh1,
                          const float* __restrict__ s_inv, char* __restrict__ wp){
  int idx = blockIdx.x*256 + threadIdx.x;
  if (idx >= 3*WPI8_STRIDE) return;
  int j    = idx & 15;
  int lane = (idx >> 4) & 63;
  int kk   = (idx >> 10) & 3;
  int tile = (idx >> 12) & 63;
  int dl   = idx >> 18;
  int g = tile & 3, s = tile >> 2;
  int n = g*256 + s*16 + (lane & 15);
  int k = kk*64 + ((lane >> 4) << 4) + j;
  const float* src = (dl < 2) ? (w_hh0 + ((size_t)dl*1024 + n)*256)
                              : (w_hh1 + (size_t)n*256);
  float v = src[k] * s_inv[dl*1024 + n];
  int q = (int)rintf(fminf(127.f, fmaxf(-127.f, v)));
  wp[idx] = (char)q;
}

__global__ void k_pack_wih1(const float* __restrict__ w, unsigned short* __restrict__ o, int n){
  int idx = blockIdx.x*256 + threadIdx.x;
  if (idx < n) o[idx] = f2bf(w[idx]);
}

// ---- full-width single-CU recurrence, i8 weights register-resident ----
// MODE 0: layer0, 16 blocks. MODE 1: layer1 fwd, 8 blocks. 512 thr = 8 waves
// (2/SIMD). Budget: 128 AGPR (breg) + <=128 VGPR -- register-dieted to avoid
// the round-8 spills (xr dropped, w_ih pre-converted, cvt_pk for bf16).
template<int MODE>
__global__ __launch_bounds__(512, 2) void k_rec8(
    const float* __restrict__ x,
    const char* __restrict__ wpack,
    const float* __restrict__ comb,
    const float* __restrict__ w_ih0,
    const float* __restrict__ b0,
    const unsigned short* __restrict__ xp,
    unsigned short* __restrict__ y0,
    float* __restrict__ hS)
{
  const int tid  = threadIdx.x;
  const int lane = tid & 63;
  const int w    = tid >> 6;            // 0..7
  int dir, bgrp, dl;
  if (MODE == 0){ dir = blockIdx.x >> 3; bgrp = blockIdx.x & 7; dl = dir; }
  else          { dir = 0; bgrp = blockIdx.x; dl = 2; }
  const int b0r = bgrp * 16;

  __shared__ __align__(16) char  A_lds[2][16*256];  // h i8, chunk-XOR swizzled
  __shared__ __align__(16) float x_lds[2][16][4];   // MODE0 x stage

  // all w_hh weights into registers (128 AGPR/wave)
  const i32x4* wpb = (const i32x4*)(wpack + (size_t)dl*WPI8_STRIDE);
  i32x4 breg[2][4][4];
  #pragma unroll
  for (int p = 0; p < 2; ++p)
    #pragma unroll
    for (int g = 0; g < 4; ++g)
      #pragma unroll
      for (int kk = 0; kk < 4; ++kk)
        breg[p][g][kk] = wpb[(((((2*w+p)*4 + g)*4) + kk) << 6) + lane];

  const int c   = lane & 15;
  const int rb  = (lane >> 4) << 2;
  const int odd = lane & 1;

  float cmb[2][4];
  #pragma unroll
  for (int p = 0; p < 2; ++p)
    #pragma unroll
    for (int g = 0; g < 4; ++g)
      cmb[p][g] = comb[dl*1024 + g*256 + (2*w+p)*16 + c];

  // MODE0: w_ih slice + bias, f32 in registers (thread-fixed, 40 regs)
  float wv[2][4][4], bia[2][4];
  if (MODE == 0){
    #pragma unroll
    for (int p = 0; p < 2; ++p)
      #pragma unroll
      for (int g = 0; g < 4; ++g){
        int col = g*256 + (2*w+p)*16 + c;
        const float* wr = &w_ih0[(size_t)(dir*1024 + col)*4];
        wv[p][g][0] = wr[0]; wv[p][g][1] = wr[1];
        wv[p][g][2] = wr[2]; wv[p][g][3] = wr[3];
        bia[p][g] = b0[dir*1024 + col];
      }
  }

  for (int i = tid; i < 16*256; i += 512) A_lds[0][i] = 0;   // h(0) = 0
  if (MODE == 0 && tid < 64){
    int row = tid >> 2, i = tid & 3;
    int t0 = dir ? (T_LEN-1) : 0;
    x_lds[0][row][i] = x[((size_t)(b0r+row)*T_LEN + t0)*4 + i];
  }

  float c_reg[2][4];
  #pragma unroll
  for (int p = 0; p < 2; ++p)
    #pragma unroll
    for (int r = 0; r < 4; ++r) c_reg[p][r] = 0.f;

  // MODE1: double-buffered C-in gates
  uint2 cinC[2][4], cinN[2][4];
  if (MODE == 1){
    #pragma unroll
    for (int p = 0; p < 2; ++p)
      #pragma unroll
      for (int g = 0; g < 4; ++g)
        cinC[p][g] = *(const uint2*)&xp[((((size_t)0*8 + bgrp)*16 + (2*w+p))*4 + g)*256 + c*16 + rb];
  }

  for (int tt = 0; tt < T_LEN; ++tt){
    const int t = (MODE == 0 && dir) ? (T_LEN-1-tt) : tt;
    const char* Ac = A_lds[tt & 1];
    char* An = (char*)A_lds[(tt + 1) & 1];

    __syncthreads();   // h(tt)/x(tt) complete in Ac

    // A fragments (h i8), swizzle-read
    i32x4 a[4];
    #pragma unroll
    for (int kk = 0; kk < 4; ++kk)
      a[kk] = *(const i32x4*)&Ac[(c << 8) + ((((kk << 2) + (lane >> 4)) ^ c) << 4)];

    // MODE1: issue NEXT step's cin loads (latency hides under MFMA+elementwise)
    if (MODE == 1){
      int tn = (t + 1 < T_LEN) ? t + 1 : t;
      #pragma unroll
      for (int p = 0; p < 2; ++p)
        #pragma unroll
        for (int g = 0; g < 4; ++g)
          cinN[p][g] = *(const uint2*)&xp[((((size_t)tn*8 + bgrp)*16 + (2*w+p))*4 + g)*256 + c*16 + rb];
    }

    // MFMA: all B from registers
    i32x4 acc[2][4];
    #pragma unroll
    for (int p = 0; p < 2; ++p)
      #pragma unroll
      for (int g = 0; g < 4; ++g){
        acc[p][g] = (i32x4){0,0,0,0};
        #pragma unroll
        for (int kk = 0; kk < 4; ++kk)
          acc[p][g] = __builtin_amdgcn_mfma_i32_16x16x64_i8(a[kk], breg[p][g][kk], acc[p][g], 0, 0, 0);
      }

    // ---- elementwise: dequant + x/cin + LSTM cell + h re-quant ----
    #pragma unroll
    for (int p = 0; p < 2; ++p){
      const int jc = (2*w+p)*16 + c;
      float hvf[4];
      #pragma unroll
      for (int r = 0; r < 4; ++r){
        float gv[4];
        if (MODE == 0){
          float4 xv = *(const float4*)&x_lds[tt & 1][rb + r][0];
          #pragma unroll
          for (int g = 0; g < 4; ++g){
            gv[g] = fmaf((float)acc[p][g][r], cmb[p][g], bia[p][g]);
            gv[g] = fmaf(xv.x, wv[p][g][0], gv[g]);
            gv[g] = fmaf(xv.y, wv[p][g][1], gv[g]);
            gv[g] = fmaf(xv.z, wv[p][g][2], gv[g]);
            gv[g] = fmaf(xv.w, wv[p][g][3], gv[g]);
          }
        } else {
          #pragma unroll
          for (int g = 0; g < 4; ++g){
            unsigned uu = (r < 2) ? cinC[p][g].x : cinC[p][g].y;
            float ci = bf2f((unsigned short)((r & 1) ? (uu >> 16) : (uu & 0xFFFF)));
            gv[g] = fmaf((float)acc[p][g][r], cmb[p][g], ci);
          }
        }
        float cc = sigmf(gv[1])*c_reg[p][r] + sigmf(gv[0])*tanhf_(gv[2]);
        c_reg[p][r] = cc;
        float h = sigmf(gv[3])*tanhf_(cc);
        hvf[r] = h;
        int row = rb + r;
        float hcl = fminf(127.f, fmaxf(-127.f, h*127.f));
        An[(row << 8) + ((((jc >> 4) ^ row)) << 4) + (jc & 15)] = (char)__float2int_rn(hcl);
        if (MODE == 1 && tt == T_LEN-1)
          hS[(size_t)(b0r + row)*HID + jc] = h;
      }
      if (MODE == 0){
        // HW bf16 pack (RNE) + lane-pair shuffle -> u32 y0 stores
        unsigned pk0, pk1;
        asm("v_cvt_pk_bf16_f32 %0, %1, %2" : "=v"(pk0) : "v"(hvf[0]), "v"(hvf[1]));
        asm("v_cvt_pk_bf16_f32 %0, %1, %2" : "=v"(pk1) : "v"(hvf[2]), "v"(hvf[3]));
        unsigned nb0 = (unsigned)__shfl_xor((int)pk0, 1, 64);
        unsigned nb1 = (unsigned)__shfl_xor((int)pk1, 1, 64);
        unsigned s0v = odd ? ((nb1 & 0xFFFFu) | (pk1 << 16))
                           : ((pk0 & 0xFFFFu) | (nb0 << 16));
        unsigned s1v = odd ? ((nb1 >> 16) | (pk1 & 0xFFFF0000u))
                           : ((pk0 >> 16) | (nb0 & 0xFFFF0000u));
        int r0 = rb + (odd ? 2 : 0);
        int colu = jc & ~1;
        *(unsigned*)&y0[((size_t)t*BATCH + (b0r + r0    ))*(2*HID) + dir*HID + colu] = s0v;
        *(unsigned*)&y0[((size_t)t*BATCH + (b0r + r0 + 1))*(2*HID) + dir*HID + colu] = s1v;
      }
    }

    if (MODE == 0 && tid < 64){   // stage x(next)
      int tn = dir ? (t > 0 ? t-1 : 0) : (t < T_LEN-1 ? t+1 : t);
      int row = tid >> 2, i = tid & 3;
      x_lds[(tt + 1) & 1][row][i] = x[((size_t)(b0r+row)*T_LEN + tn)*4 + i];
    }

    if (MODE == 1){
      #pragma unroll
      for (int p = 0; p < 2; ++p)
        #pragma unroll
        for (int g = 0; g < 4; ++g) cinC[p][g] = cinN[p][g];
    }
  }
}

// ---- bf16 MFMA GEMM: C[M][1024] = A[M][512] * B[1024][512]^T + bias ----
template<int PLAIN>
__global__ __launch_bounds__(256) void k_gemm_bf(
    const unsigned short* __restrict__ A, const unsigned short* __restrict__ B,
    const float* __restrict__ bias, unsigned short* __restrict__ outF, float* __restrict__ outP)
{
  __shared__ __align__(16) unsigned short As[128*64];
  __shared__ __align__(16) unsigned short Bs[128*64];
  const int tid  = threadIdx.x;
  const int lane = tid & 63;
  const int w = tid >> 6, wm = w >> 1, wn = w & 1;
  const int t  = blockIdx.y;
  const int n0 = blockIdx.x * 128;

  f32x4 acc[4][4];
  #pragma unroll
  for (int i = 0; i < 4; ++i)
    #pragma unroll
    for (int jx = 0; jx < 4; ++jx) acc[i][jx] = (f32x4){0.f,0.f,0.f,0.f};

  const int sr = tid >> 3;
  const int sq = tid & 7;

  for (int k0 = 0; k0 < 512; k0 += 64){
    #pragma unroll
    for (int it = 0; it < 4; ++it){
      int r = sr + it*32;
      uint4 av = *(const uint4*)&A[((size_t)t*128 + r)*512 + k0 + sq*8];
      uint4 bv = *(const uint4*)&B[((size_t)(n0 + r))*512 + k0 + sq*8];
      *(uint4*)&As[r*64 + (sq ^ (r & 7))*8] = av;
      *(uint4*)&Bs[r*64 + (sq ^ (r & 7))*8] = bv;
    }
    __syncthreads();
    bf16x8 af[4][2], bfv[4][2];
    #pragma unroll
    for (int mt = 0; mt < 4; ++mt)
      #pragma unroll
      for (int kk = 0; kk < 2; ++kk){
        int row = wm*64 + mt*16 + (lane & 15);
        af[mt][kk] = *(const bf16x8*)&As[row*64 + ((kk*4 + (lane>>4)) ^ (row & 7))*8];
      }
    #pragma unroll
    for (int nl = 0; nl < 4; ++nl)
      #pragma unroll
      for (int kk = 0; kk < 2; ++kk){
        int row = wn*64 + nl*16 + (lane & 15);
        bfv[nl][kk] = *(const bf16x8*)&Bs[row*64 + ((kk*4 + (lane>>4)) ^ (row & 7))*8];
      }
    #pragma unroll
    for (int mt = 0; mt < 4; ++mt)
      #pragma unroll
      for (int nl = 0; nl < 4; ++nl){
        acc[mt][nl] = __builtin_amdgcn_mfma_f32_16x16x32_bf16(af[mt][0], bfv[nl][0], acc[mt][nl], 0,0,0);
        acc[mt][nl] = __builtin_amdgcn_mfma_f32_16x16x32_bf16(af[mt][1], bfv[nl][1], acc[mt][nl], 0,0,0);
      }
    __syncthreads();
  }

  #pragma unroll
  for (int mt = 0; mt < 4; ++mt){
    #pragma unroll
    for (int nl = 0; nl < 4; ++nl){
      int ng = n0 + wn*64 + nl*16 + (lane & 15);
      float bv = bias[ng];
      f32x4 v = acc[mt][nl];
      if (PLAIN){
        int mrow = wm*64 + mt*16 + (lane >> 4)*4;
        #pragma unroll
        for (int r = 0; r < 4; ++r)
          outP[((size_t)t*128 + mrow + r)*G4 + ng] = v[r] + bv;
      } else {
        int bgrp = wm*4 + mt;
        int s  = (ng >> 4) & 15;
        int g  = ng >> 8;
        int cg = ng & 15;
        unsigned short hb[4];
        #pragma unroll
        for (int r = 0; r < 4; ++r) hb[r] = f2bf(v[r] + bv);
        *(uint2*)&outF[((((size_t)t*8 + bgrp)*16 + s)*4 + g)*256 + cg*16 + ((lane >> 4) << 2)] = *(uint2*)hb;
      }
    }
  }
}

// ---- final: layer-1 bwd single step + combine + out proj + softmax ----
__global__ __launch_bounds__(256) void k_final(const float* __restrict__ hS,
                                               const float* __restrict__ xp1b,
                                               const float* __restrict__ w_out,
                                               const float* __restrict__ b_out,
                                               float* __restrict__ out)
{
  const int b = blockIdx.x, j = threadIdx.x;
  float iv = xp1b[b*G4 + 0*HID + j];
  float gv = xp1b[b*G4 + 2*HID + j];
  float ov = xp1b[b*G4 + 3*HID + j];
  float c  = sigmf(iv)*tanhf_(gv);
  float hb = sigmf(ov)*tanhf_(c);
  float last = hS[b*HID + j] + hb;

  __shared__ float part[3][256];
  part[0][j] = last * w_out[0*HID + j];
  part[1][j] = last * w_out[1*HID + j];
  part[2][j] = last * w_out[2*HID + j];
  __syncthreads();
  for (int s = 128; s > 0; s >>= 1){
    if (j < s){
      part[0][j] += part[0][j+s];
      part[1][j] += part[1][j+s];
      part[2][j] += part[2][j+s];
    }
    __syncthreads();
  }
  if (j == 0){
    float l0 = part[0][0] + b_out[0];
    float l1 = part[1][0] + b_out[1];
    float l2 = part[2][0] + b_out[2];
    float m = fmaxf(l0, fmaxf(l1, l2));
    float e0 = __expf(l0-m), e1 = __expf(l1-m), e2 = __expf(l2-m);
    float s = e0 + e1 + e2;
    out[b*3+0] = e0/s; out[b*3+1] = e1/s; out[b*3+2] = e2/s;
  }
}

extern "C" void kernel_launch(void* const* d_in, const int* in_sizes, int n_in,
                              void* d_out, int out_size, void* d_ws, size_t ws_size,
                              hipStream_t stream) {
  const float* x     = (const float*)d_in[0];
  const float* w_ih0 = (const float*)d_in[1];
  const float* w_hh0 = (const float*)d_in[2];
  const float* b0p   = (const float*)d_in[3];
  const float* w_ih1 = (const float*)d_in[4];
  const float* w_hh1 = (const float*)d_in[5];
  const float* b1p   = (const float*)d_in[6];
  const float* w_out = (const float*)d_in[7];
  const float* b_out = (const float*)d_in[8];
  float* out = (float*)d_out;

  // workspace layout
  unsigned short* y0    = (unsigned short*)d_ws;                 // 33,554,432 u16
  unsigned short* xp1   = y0    + (size_t)T_LEN*BATCH*2*HID;     // 67,108,864 u16
  unsigned short* wih1p = xp1   + (size_t)T_LEN*BATCH*G4;        // 1,048,576 u16
  float*          comb  = (float*)(wih1p + 2*G4*2*HID);          // 3072 f32
  float*          s_inv = comb  + 3*1024;                        // 3072 f32
  float*          xp1b  = s_inv + 3*1024;                        // 131,072 f32
  float*          hS    = xp1b  + BATCH*G4;                      // 32,768 f32
  char*           wpi8  = (char*)(hS + BATCH*HID);               // 786,432 B

  // weight prep
  k_scales<<<12, 256, 0, stream>>>(w_hh0, w_hh1, comb, s_inv);
  k_pack_i8<<<3072, 256, 0, stream>>>(w_hh0, w_hh1, s_inv, wpi8);
  k_pack_wih1<<<4096, 256, 0, stream>>>(w_ih1, wih1p, 2*G4*2*HID);

  // layer 0, both directions: full-width single-CU blocks, no exchange
  k_rec8<0><<<16, 512, 0, stream>>>(x, wpi8, comb, w_ih0, b0p, nullptr, y0, nullptr);

  // layer-1 input projection (fwd dir), frag-packed bf16 out
  k_gemm_bf<0><<<dim3(8, 512), 256, 0, stream>>>(y0, wih1p, b1p, xp1, nullptr);

  // layer-1 backward first step gates: plain fp32
  k_gemm_bf<1><<<dim3(8, 1), 256, 0, stream>>>(y0 + (size_t)(T_LEN-1)*BATCH*2*HID,
                                               wih1p + (size_t)G4*2*HID, b1p + G4,
                                               nullptr, xp1b);

  // layer 1 forward recurrence
  k_rec8<1><<<8, 512, 0, stream>>>(nullptr, wpi8, comb, nullptr, nullptr, xp1, nullptr, hS);

  k_final<<<BATCH, 256, 0, stream>>>(hS, xp1b, w_out, b_out, out);
}

// Round 10
// 2429.253 us; speedup vs baseline: 1.5308x; 1.1096x over previous
//
#include <hip/hip_runtime.h>

typedef __attribute__((ext_vector_type(8))) short bf16x8;
typedef __attribute__((ext_vector_type(4))) float f32x4;
typedef __attribute__((ext_vector_type(4))) int   i32x4;

#define T_LEN 512
#define BATCH 128
#define HID   256
#define G4    1024
#define WPI8_STRIDE 262144   // bytes per dir-layer: 64 tiles * 4 kk * 64 lanes * 16

__device__ __forceinline__ float sigmf(float x){
  return __builtin_amdgcn_rcpf(1.0f + __expf(-x));
}
__device__ __forceinline__ float tanhf_(float x){
  return 1.0f - 2.0f*__builtin_amdgcn_rcpf(1.0f + __expf(2.0f*x));
}
__device__ __forceinline__ unsigned short f2bf(float f){
  union{float f;unsigned u;} v; v.f=f;
  unsigned r = v.u + 0x7FFF + ((v.u>>16)&1);
  return (unsigned short)(r>>16);
}
__device__ __forceinline__ float bf2f(unsigned short b){
  union{unsigned u;float f;} v; v.u = ((unsigned)b)<<16; return v.f;
}

// ---- per-column scales for i8 quantization ----
__global__ void k_scales(const float* __restrict__ w_hh0, const float* __restrict__ w_hh1,
                         float* __restrict__ comb, float* __restrict__ s_inv){
  int idx = blockIdx.x*256 + threadIdx.x;
  if (idx >= 3*1024) return;
  int dl = idx >> 10, n = idx & 1023;
  const float* src = (dl < 2) ? (w_hh0 + ((size_t)dl*1024 + n)*256)
                              : (w_hh1 + (size_t)n*256);
  float m = 1e-20f;
  for (int k = 0; k < 256; k += 4){
    float4 v = *(const float4*)&src[k];
    m = fmaxf(m, fmaxf(fmaxf(fabsf(v.x), fabsf(v.y)), fmaxf(fabsf(v.z), fabsf(v.w))));
  }
  s_inv[idx] = 127.f / m;
  comb[idx]  = m / 16129.f;
}

// ---- pack w_hh into i8 B-fragment order ----
__global__ void k_pack_i8(const float* __restrict__ w_hh0, const float* __restrict__ w_hh1,
                          const float* __restrict__ s_inv, char* __restrict__ wp){
  int idx = blockIdx.x*256 + threadIdx.x;
  if (idx >= 3*WPI8_STRIDE) return;
  int j    = idx & 15;
  int lane = (idx >> 4) & 63;
  int kk   = (idx >> 10) & 3;
  int tile = (idx >> 12) & 63;
  int dl   = idx >> 18;
  int g = tile & 3, s = tile >> 2;
  int n = g*256 + s*16 + (lane & 15);
  int k = kk*64 + ((lane >> 4) << 4) + j;
  const float* src = (dl < 2) ? (w_hh0 + ((size_t)dl*1024 + n)*256)
                              : (w_hh1 + (size_t)n*256);
  float v = src[k] * s_inv[dl*1024 + n];
  int q = (int)rintf(fminf(127.f, fmaxf(-127.f, v)));
  wp[idx] = (char)q;
}

__global__ void k_pack_wih1(const float* __restrict__ w, unsigned short* __restrict__ o, int n){
  int idx = blockIdx.x*256 + threadIdx.x;
  if (idx < n) o[idx] = f2bf(w[idx]);
}

// ---- full-width single-CU recurrence, i8 weights register-resident ----
// MODE 0: layer0, 16 blocks. MODE 1: layer1 fwd, 8 blocks. 512 thr = 8 waves
// (2/SIMD). Round-10 change: w_ih/bias moved from 40 thread-regs to raw LDS
// (broadcast-read per step) -> MODE0 fits 256-reg budget, no spills.
template<int MODE>
__global__ __launch_bounds__(512, 2) void k_rec8(
    const float* __restrict__ x,
    const char* __restrict__ wpack,
    const float* __restrict__ comb,
    const float* __restrict__ w_ih0,
    const float* __restrict__ b0,
    const unsigned short* __restrict__ xp,
    unsigned short* __restrict__ y0,
    float* __restrict__ hS)
{
  const int tid  = threadIdx.x;
  const int lane = tid & 63;
  const int w    = tid >> 6;            // 0..7
  int dir, bgrp, dl;
  if (MODE == 0){ dir = blockIdx.x >> 3; bgrp = blockIdx.x & 7; dl = dir; }
  else          { dir = 0; bgrp = blockIdx.x; dl = 2; }
  const int b0r = bgrp * 16;

  __shared__ __align__(16) char   A_lds[2][16*256];  // h i8, chunk-XOR swizzled
  __shared__ __align__(16) float  x_lds[2][16][4];   // MODE0 x stage
  __shared__ __align__(16) float4 wv_lds[1024];      // MODE0 w_ih[dir], raw
  __shared__            float     bia_lds[1024];     // MODE0 bias[dir]

  // all w_hh weights into registers (128 AGPR/wave)
  const i32x4* wpb = (const i32x4*)(wpack + (size_t)dl*WPI8_STRIDE);
  i32x4 breg[2][4][4];
  #pragma unroll
  for (int p = 0; p < 2; ++p)
    #pragma unroll
    for (int g = 0; g < 4; ++g)
      #pragma unroll
      for (int kk = 0; kk < 4; ++kk)
        breg[p][g][kk] = wpb[(((((2*w+p)*4 + g)*4) + kk) << 6) + lane];

  const int c   = lane & 15;
  const int rb  = (lane >> 4) << 2;
  const int odd = lane & 1;

  float cmb[2][4];
  #pragma unroll
  for (int p = 0; p < 2; ++p)
    #pragma unroll
    for (int g = 0; g < 4; ++g)
      cmb[p][g] = comb[dl*1024 + g*256 + (2*w+p)*16 + c];

  for (int i = tid; i < 16*256; i += 512) A_lds[0][i] = 0;   // h(0) = 0
  if (MODE == 0){
    for (int i = tid; i < 1024; i += 512){
      wv_lds[i]  = *(const float4*)&w_ih0[(size_t)(dir*1024 + i)*4];
      bia_lds[i] = b0[dir*1024 + i];
    }
    if (tid < 64){
      int row = tid >> 2, i = tid & 3;
      int t0 = dir ? (T_LEN-1) : 0;
      x_lds[0][row][i] = x[((size_t)(b0r+row)*T_LEN + t0)*4 + i];
    }
  }

  float c_reg[2][4];
  #pragma unroll
  for (int p = 0; p < 2; ++p)
    #pragma unroll
    for (int r = 0; r < 4; ++r) c_reg[p][r] = 0.f;

  // MODE1: double-buffered C-in gates
  uint2 cinC[2][4], cinN[2][4];
  if (MODE == 1){
    #pragma unroll
    for (int p = 0; p < 2; ++p)
      #pragma unroll
      for (int g = 0; g < 4; ++g)
        cinC[p][g] = *(const uint2*)&xp[((((size_t)0*8 + bgrp)*16 + (2*w+p))*4 + g)*256 + c*16 + rb];
  }

  for (int tt = 0; tt < T_LEN; ++tt){
    const int t = (MODE == 0 && dir) ? (T_LEN-1-tt) : tt;
    const char* Ac = A_lds[tt & 1];
    char* An = (char*)A_lds[(tt + 1) & 1];

    __syncthreads();   // h(tt)/x(tt) complete in Ac (also covers init writes)

    // A fragments (h i8), swizzle-read
    i32x4 a[4];
    #pragma unroll
    for (int kk = 0; kk < 4; ++kk)
      a[kk] = *(const i32x4*)&Ac[(c << 8) + ((((kk << 2) + (lane >> 4)) ^ c) << 4)];

    // MODE1: issue NEXT step's cin loads (latency hides under MFMA+elementwise)
    if (MODE == 1){
      int tn = (t + 1 < T_LEN) ? t + 1 : t;
      #pragma unroll
      for (int p = 0; p < 2; ++p)
        #pragma unroll
        for (int g = 0; g < 4; ++g)
          cinN[p][g] = *(const uint2*)&xp[((((size_t)tn*8 + bgrp)*16 + (2*w+p))*4 + g)*256 + c*16 + rb];
    }

    // MFMA: all B from registers
    i32x4 acc[2][4];
    #pragma unroll
    for (int p = 0; p < 2; ++p)
      #pragma unroll
      for (int g = 0; g < 4; ++g){
        acc[p][g] = (i32x4){0,0,0,0};
        #pragma unroll
        for (int kk = 0; kk < 4; ++kk)
          acc[p][g] = __builtin_amdgcn_mfma_i32_16x16x64_i8(a[kk], breg[p][g][kk], acc[p][g], 0, 0, 0);
      }

    // MODE0: x rows for this lane (LDS, reused across both p)
    float4 xr[4];
    if (MODE == 0){
      #pragma unroll
      for (int r = 0; r < 4; ++r)
        xr[r] = *(const float4*)&x_lds[tt & 1][rb + r][0];
    }

    // ---- elementwise: dequant + x/cin + LSTM cell + h re-quant ----
    #pragma unroll
    for (int p = 0; p < 2; ++p){
      const int jc = (2*w+p)*16 + c;
      // MODE0: per-step broadcast reads of w_ih slice + bias (scoped temps)
      float4 wvv[4]; float bb[4];
      if (MODE == 0){
        #pragma unroll
        for (int g = 0; g < 4; ++g){
          wvv[g] = wv_lds[g*256 + jc];
          bb[g]  = bia_lds[g*256 + jc];
        }
      }
      float hvf[4];
      #pragma unroll
      for (int r = 0; r < 4; ++r){
        float gv[4];
        if (MODE == 0){
          #pragma unroll
          for (int g = 0; g < 4; ++g){
            float t0 = fmaf(xr[r].x, wvv[g].x, bb[g]);
            t0 = fmaf(xr[r].y, wvv[g].y, t0);
            t0 = fmaf(xr[r].z, wvv[g].z, t0);
            t0 = fmaf(xr[r].w, wvv[g].w, t0);
            gv[g] = fmaf((float)acc[p][g][r], cmb[p][g], t0);
          }
        } else {
          #pragma unroll
          for (int g = 0; g < 4; ++g){
            unsigned uu = (r < 2) ? cinC[p][g].x : cinC[p][g].y;
            float ci = bf2f((unsigned short)((r & 1) ? (uu >> 16) : (uu & 0xFFFF)));
            gv[g] = fmaf((float)acc[p][g][r], cmb[p][g], ci);
          }
        }
        float cc = sigmf(gv[1])*c_reg[p][r] + sigmf(gv[0])*tanhf_(gv[2]);
        c_reg[p][r] = cc;
        float h = sigmf(gv[3])*tanhf_(cc);
        hvf[r] = h;
        int row = rb + r;
        float hcl = fminf(127.f, fmaxf(-127.f, h*127.f));
        An[(row << 8) + ((((jc >> 4) ^ row)) << 4) + (jc & 15)] = (char)__float2int_rn(hcl);
        if (MODE == 1 && tt == T_LEN-1)
          hS[(size_t)(b0r + row)*HID + jc] = h;
      }
      if (MODE == 0){
        // HW bf16 pack (RNE) + lane-pair shuffle -> u32 y0 stores
        unsigned pk0, pk1;
        asm("v_cvt_pk_bf16_f32 %0, %1, %2" : "=v"(pk0) : "v"(hvf[0]), "v"(hvf[1]));
        asm("v_cvt_pk_bf16_f32 %0, %1, %2" : "=v"(pk1) : "v"(hvf[2]), "v"(hvf[3]));
        unsigned nb0 = (unsigned)__shfl_xor((int)pk0, 1, 64);
        unsigned nb1 = (unsigned)__shfl_xor((int)pk1, 1, 64);
        unsigned s0v = odd ? ((nb1 & 0xFFFFu) | (pk1 << 16))
                           : ((pk0 & 0xFFFFu) | (nb0 << 16));
        unsigned s1v = odd ? ((nb1 >> 16) | (pk1 & 0xFFFF0000u))
                           : ((pk0 >> 16) | (nb0 & 0xFFFF0000u));
        int r0 = rb + (odd ? 2 : 0);
        int colu = jc & ~1;
        *(unsigned*)&y0[((size_t)t*BATCH + (b0r + r0    ))*(2*HID) + dir*HID + colu] = s0v;
        *(unsigned*)&y0[((size_t)t*BATCH + (b0r + r0 + 1))*(2*HID) + dir*HID + colu] = s1v;
      }
    }

    if (MODE == 0 && tid < 64){   // stage x(next)
      int tn = dir ? (t > 0 ? t-1 : 0) : (t < T_LEN-1 ? t+1 : t);
      int row = tid >> 2, i = tid & 3;
      x_lds[(tt + 1) & 1][row][i] = x[((size_t)(b0r+row)*T_LEN + tn)*4 + i];
    }

    if (MODE == 1){
      #pragma unroll
      for (int p = 0; p < 2; ++p)
        #pragma unroll
        for (int g = 0; g < 4; ++g) cinC[p][g] = cinN[p][g];
    }
  }
}

// ---- bf16 MFMA GEMM: C[M][1024] = A[M][512] * B[1024][512]^T + bias ----
template<int PLAIN>
__global__ __launch_bounds__(256) void k_gemm_bf(
    const unsigned short* __restrict__ A, const unsigned short* __restrict__ B,
    const float* __restrict__ bias, unsigned short* __restrict__ outF, float* __restrict__ outP)
{
  __shared__ __align__(16) unsigned short As[128*64];
  __shared__ __align__(16) unsigned short Bs[128*64];
  const int tid  = threadIdx.x;
  const int lane = tid & 63;
  const int w = tid >> 6, wm = w >> 1, wn = w & 1;
  const int t  = blockIdx.y;
  const int n0 = blockIdx.x * 128;

  f32x4 acc[4][4];
  #pragma unroll
  for (int i = 0; i < 4; ++i)
    #pragma unroll
    for (int jx = 0; jx < 4; ++jx) acc[i][jx] = (f32x4){0.f,0.f,0.f,0.f};

  const int sr = tid >> 3;
  const int sq = tid & 7;

  for (int k0 = 0; k0 < 512; k0 += 64){
    #pragma unroll
    for (int it = 0; it < 4; ++it){
      int r = sr + it*32;
      uint4 av = *(const uint4*)&A[((size_t)t*128 + r)*512 + k0 + sq*8];
      uint4 bv = *(const uint4*)&B[((size_t)(n0 + r))*512 + k0 + sq*8];
      *(uint4*)&As[r*64 + (sq ^ (r & 7))*8] = av;
      *(uint4*)&Bs[r*64 + (sq ^ (r & 7))*8] = bv;
    }
    __syncthreads();
    bf16x8 af[4][2], bfv[4][2];
    #pragma unroll
    for (int mt = 0; mt < 4; ++mt)
      #pragma unroll
      for (int kk = 0; kk < 2; ++kk){
        int row = wm*64 + mt*16 + (lane & 15);
        af[mt][kk] = *(const bf16x8*)&As[row*64 + ((kk*4 + (lane>>4)) ^ (row & 7))*8];
      }
    #pragma unroll
    for (int nl = 0; nl < 4; ++nl)
      #pragma unroll
      for (int kk = 0; kk < 2; ++kk){
        int row = wn*64 + nl*16 + (lane & 15);
        bfv[nl][kk] = *(const bf16x8*)&Bs[row*64 + ((kk*4 + (lane>>4)) ^ (row & 7))*8];
      }
    #pragma unroll
    for (int mt = 0; mt < 4; ++mt)
      #pragma unroll
      for (int nl = 0; nl < 4; ++nl){
        acc[mt][nl] = __builtin_amdgcn_mfma_f32_16x16x32_bf16(af[mt][0], bfv[nl][0], acc[mt][nl], 0,0,0);
        acc[mt][nl] = __builtin_amdgcn_mfma_f32_16x16x32_bf16(af[mt][1], bfv[nl][1], acc[mt][nl], 0,0,0);
      }
    __syncthreads();
  }

  #pragma unroll
  for (int mt = 0; mt < 4; ++mt){
    #pragma unroll
    for (int nl = 0; nl < 4; ++nl){
      int ng = n0 + wn*64 + nl*16 + (lane & 15);
      float bv = bias[ng];
      f32x4 v = acc[mt][nl];
      if (PLAIN){
        int mrow = wm*64 + mt*16 + (lane >> 4)*4;
        #pragma unroll
        for (int r = 0; r < 4; ++r)
          outP[((size_t)t*128 + mrow + r)*G4 + ng] = v[r] + bv;
      } else {
        int bgrp = wm*4 + mt;
        int s  = (ng >> 4) & 15;
        int g  = ng >> 8;
        int cg = ng & 15;
        unsigned short hb[4];
        #pragma unroll
        for (int r = 0; r < 4; ++r) hb[r] = f2bf(v[r] + bv);
        *(uint2*)&outF[((((size_t)t*8 + bgrp)*16 + s)*4 + g)*256 + cg*16 + ((lane >> 4) << 2)] = *(uint2*)hb;
      }
    }
  }
}

// ---- final: layer-1 bwd single step + combine + out proj + softmax ----
__global__ __launch_bounds__(256) void k_final(const float* __restrict__ hS,
                                               const float* __restrict__ xp1b,
                                               const float* __restrict__ w_out,
                                               const float* __restrict__ b_out,
                                               float* __restrict__ out)
{
  const int b = blockIdx.x, j = threadIdx.x;
  float iv = xp1b[b*G4 + 0*HID + j];
  float gv = xp1b[b*G4 + 2*HID + j];
  float ov = xp1b[b*G4 + 3*HID + j];
  float c  = sigmf(iv)*tanhf_(gv);
  float hb = sigmf(ov)*tanhf_(c);
  float last = hS[b*HID + j] + hb;

  __shared__ float part[3][256];
  part[0][j] = last * w_out[0*HID + j];
  part[1][j] = last * w_out[1*HID + j];
  part[2][j] = last * w_out[2*HID + j];
  __syncthreads();
  for (int s = 128; s > 0; s >>= 1){
    if (j < s){
      part[0][j] += part[0][j+s];
      part[1][j] += part[1][j+s];
      part[2][j] += part[2][j+s];
    }
    __syncthreads();
  }
  if (j == 0){
    float l0 = part[0][0] + b_out[0];
    float l1 = part[1][0] + b_out[1];
    float l2 = part[2][0] + b_out[2];
    float m = fmaxf(l0, fmaxf(l1, l2));
    float e0 = __expf(l0-m), e1 = __expf(l1-m), e2 = __expf(l2-m);
    float s = e0 + e1 + e2;
    out[b*3+0] = e0/s; out[b*3+1] = e1/s; out[b*3+2] = e2/s;
  }
}

extern "C" void kernel_launch(void* const* d_in, const int* in_sizes, int n_in,
                              void* d_out, int out_size, void* d_ws, size_t ws_size,
                              hipStream_t stream) {
  const float* x     = (const float*)d_in[0];
  const float* w_ih0 = (const float*)d_in[1];
  const float* w_hh0 = (const float*)d_in[2];
  const float* b0p   = (const float*)d_in[3];
  const float* w_ih1 = (const float*)d_in[4];
  const float* w_hh1 = (const float*)d_in[5];
  const float* b1p   = (const float*)d_in[6];
  const float* w_out = (const float*)d_in[7];
  const float* b_out = (const float*)d_in[8];
  float* out = (float*)d_out;

  // workspace layout
  unsigned short* y0    = (unsigned short*)d_ws;                 // 33,554,432 u16
  unsigned short* xp1   = y0    + (size_t)T_LEN*BATCH*2*HID;     // 67,108,864 u16
  unsigned short* wih1p = xp1   + (size_t)T_LEN*BATCH*G4;        // 1,048,576 u16
  float*          comb  = (float*)(wih1p + 2*G4*2*HID);          // 3072 f32
  float*          s_inv = comb  + 3*1024;                        // 3072 f32
  float*          xp1b  = s_inv + 3*1024;                        // 131,072 f32
  float*          hS    = xp1b  + BATCH*G4;                      // 32,768 f32
  char*           wpi8  = (char*)(hS + BATCH*HID);               // 786,432 B

  // weight prep
  k_scales<<<12, 256, 0, stream>>>(w_hh0, w_hh1, comb, s_inv);
  k_pack_i8<<<3072, 256, 0, stream>>>(w_hh0, w_hh1, s_inv, wpi8);
  k_pack_wih1<<<4096, 256, 0, stream>>>(w_ih1, wih1p, 2*G4*2*HID);

  // layer 0, both directions: full-width single-CU blocks, no exchange
  k_rec8<0><<<16, 512, 0, stream>>>(x, wpi8, comb, w_ih0, b0p, nullptr, y0, nullptr);

  // layer-1 input projection (fwd dir), frag-packed bf16 out
  k_gemm_bf<0><<<dim3(8, 512), 256, 0, stream>>>(y0, wih1p, b1p, xp1, nullptr);

  // layer-1 backward first step gates: plain fp32
  k_gemm_bf<1><<<dim3(8, 1), 256, 0, stream>>>(y0 + (size_t)(T_LEN-1)*BATCH*2*HID,
                                               wih1p + (size_t)G4*2*HID, b1p + G4,
                                               nullptr, xp1b);

  // layer 1 forward recurrence
  k_rec8<1><<<8, 512, 0, stream>>>(nullptr, wpi8, comb, nullptr, nullptr, xp1, nullptr, hS);

  k_final<<<BATCH, 256, 0, stream>>>(hS, xp1b, w_out, b_out, out);
}

// Round 11
// 1725.508 us; speedup vs baseline: 2.1551x; 1.4078x over previous
//
#include <hip/hip_runtime.h>

typedef __attribute__((ext_vector_type(8))) short bf16x8;
typedef __attribute__((ext_vector_type(4))) float f32x4;
typedef __attribute__((ext_vector_type(4))) int   i32x4;

#define T_LEN 512
#define BATCH 128
#define HID   256
#define G4    1024
#define WPI8_STRIDE 262144   // bytes per dir-layer: 64 tiles * 4 kk * 64 lanes * 16

__device__ __forceinline__ float sigmf(float x){
  return __builtin_amdgcn_rcpf(1.0f + __expf(-x));
}
__device__ __forceinline__ float tanhf_(float x){
  return 1.0f - 2.0f*__builtin_amdgcn_rcpf(1.0f + __expf(2.0f*x));
}
__device__ __forceinline__ unsigned short f2bf(float f){
  union{float f;unsigned u;} v; v.f=f;
  unsigned r = v.u + 0x7FFF + ((v.u>>16)&1);
  return (unsigned short)(r>>16);
}
__device__ __forceinline__ float bf2f(unsigned short b){
  union{unsigned u;float f;} v; v.u = ((unsigned)b)<<16; return v.f;
}

// ---- per-column scales for i8 quantization ----
__global__ void k_scales(const float* __restrict__ w_hh0, const float* __restrict__ w_hh1,
                         float* __restrict__ comb, float* __restrict__ s_inv){
  int idx = blockIdx.x*256 + threadIdx.x;
  if (idx >= 3*1024) return;
  int dl = idx >> 10, n = idx & 1023;
  const float* src = (dl < 2) ? (w_hh0 + ((size_t)dl*1024 + n)*256)
                              : (w_hh1 + (size_t)n*256);
  float m = 1e-20f;
  for (int k = 0; k < 256; k += 4){
    float4 v = *(const float4*)&src[k];
    m = fmaxf(m, fmaxf(fmaxf(fabsf(v.x), fabsf(v.y)), fmaxf(fabsf(v.z), fabsf(v.w))));
  }
  s_inv[idx] = 127.f / m;
  comb[idx]  = m / 16129.f;
}

// ---- pack w_hh into i8 B-fragment order ----
__global__ void k_pack_i8(const float* __restrict__ w_hh0, const float* __restrict__ w_hh1,
                          const float* __restrict__ s_inv, char* __restrict__ wp){
  int idx = blockIdx.x*256 + threadIdx.x;
  if (idx >= 3*WPI8_STRIDE) return;
  int j    = idx & 15;
  int lane = (idx >> 4) & 63;
  int kk   = (idx >> 10) & 3;
  int tile = (idx >> 12) & 63;
  int dl   = idx >> 18;
  int g = tile & 3, s = tile >> 2;
  int n = g*256 + s*16 + (lane & 15);
  int k = kk*64 + ((lane >> 4) << 4) + j;
  const float* src = (dl < 2) ? (w_hh0 + ((size_t)dl*1024 + n)*256)
                              : (w_hh1 + (size_t)n*256);
  float v = src[k] * s_inv[dl*1024 + n];
  int q = (int)rintf(fminf(127.f, fmaxf(-127.f, v)));
  wp[idx] = (char)q;
}

__global__ void k_pack_wih1(const float* __restrict__ w, unsigned short* __restrict__ o, int n){
  int idx = blockIdx.x*256 + threadIdx.x;
  if (idx < n) o[idx] = f2bf(w[idx]);
}

// ---- full-width single-CU recurrence, i8 weights register-resident ----
// Round-11: batch-8 blocks (2x CU count; VALU-bound elementwise halves per CU).
// MODE 0: layer0, 32 blocks (dir x 16 bgrp). MODE 1: layer1 fwd, 16 blocks.
// 512 thr = 8 waves (2/SIMD). After MFMA (M=16, rows 8-15 zero), p=1 gates are
// shfl_xor(32)-redistributed to lanes 32-63 so ALL lanes do 4 cells each.
template<int MODE>
__global__ __launch_bounds__(512, 2) void k_rec8(
    const float* __restrict__ x,
    const char* __restrict__ wpack,
    const float* __restrict__ comb,
    const float* __restrict__ w_ih0,
    const float* __restrict__ b0,
    const unsigned short* __restrict__ xp,
    unsigned short* __restrict__ y0,
    float* __restrict__ hS)
{
  const int tid  = threadIdx.x;
  const int lane = tid & 63;
  const int w    = tid >> 6;            // 0..7
  int dir, bgrp, dl;
  if (MODE == 0){ dir = blockIdx.x >> 4; bgrp = blockIdx.x & 15; dl = dir; }
  else          { dir = 0; bgrp = blockIdx.x; dl = 2; }
  const int b0r = bgrp * 8;

  __shared__ __align__(16) char   A_lds[2][16*256];  // h i8 (rows 0-7 live, 8-15 zero)
  __shared__ __align__(16) float  x_lds[2][8][4];    // MODE0 x stage
  __shared__ __align__(16) float4 wv_lds[1024];      // MODE0 w_ih[dir], raw
  __shared__            float     bia_lds[1024];     // MODE0 bias[dir]

  // all w_hh weights into registers (128 AGPR/wave)
  const i32x4* wpb = (const i32x4*)(wpack + (size_t)dl*WPI8_STRIDE);
  i32x4 breg[2][4][4];
  #pragma unroll
  for (int p = 0; p < 2; ++p)
    #pragma unroll
    for (int g = 0; g < 4; ++g)
      #pragma unroll
      for (int kk = 0; kk < 4; ++kk)
        breg[p][g][kk] = wpb[(((((2*w+p)*4 + g)*4) + kk) << 6) + lane];

  const int c    = lane & 15;
  const int half = lane >> 5;                 // which p this lane owns post-shuffle
  const int rb2  = ((lane >> 4) & 1) << 2;    // row base 0 or 4
  const int odd  = lane & 1;
  const int jc   = (2*w + half)*16 + c;       // hid col this lane owns

  float cmb_l[4];
  #pragma unroll
  for (int g = 0; g < 4; ++g)
    cmb_l[g] = comb[dl*1024 + g*256 + jc];

  for (int i = tid; i < 2*16*256; i += 512) ((char*)A_lds)[i] = 0;   // h(0)=0, rows 8-15 stay 0
  if (MODE == 0){
    for (int i = tid; i < 1024; i += 512){
      wv_lds[i]  = *(const float4*)&w_ih0[(size_t)(dir*1024 + i)*4];
      bia_lds[i] = b0[dir*1024 + i];
    }
    if (tid < 32){
      int row = tid >> 2, i = tid & 3;
      int t0 = dir ? (T_LEN-1) : 0;
      x_lds[0][row][i] = x[((size_t)(b0r+row)*T_LEN + t0)*4 + i];
    }
  }

  float c_reg[4];
  #pragma unroll
  for (int r = 0; r < 4; ++r) c_reg[r] = 0.f;

  // MODE1: double-buffered C-in gates (4 cells -> 4x uint2)
  uint2 cinC[4], cinN[4];
  if (MODE == 1){
    #pragma unroll
    for (int g = 0; g < 4; ++g)
      cinC[g] = *(const uint2*)&xp[((((size_t)0*16 + bgrp)*256 + jc)*4 + g)*8 + rb2];
  }

  for (int tt = 0; tt < T_LEN; ++tt){
    const int t = (MODE == 0 && dir) ? (T_LEN-1-tt) : tt;
    const char* Ac = A_lds[tt & 1];
    char* An = (char*)A_lds[(tt + 1) & 1];

    __syncthreads();   // h(tt)/x(tt) complete in Ac

    // A fragments (h i8), swizzle-read; rows 8-15 are zeros
    i32x4 a[4];
    #pragma unroll
    for (int kk = 0; kk < 4; ++kk)
      a[kk] = *(const i32x4*)&Ac[(c << 8) + ((((kk << 2) + (lane >> 4)) ^ c) << 4)];

    // MODE1: issue NEXT step's cin loads (latency hides under MFMA+elementwise)
    if (MODE == 1){
      int tn = (t + 1 < T_LEN) ? t + 1 : t;
      #pragma unroll
      for (int g = 0; g < 4; ++g)
        cinN[g] = *(const uint2*)&xp[((((size_t)tn*16 + bgrp)*256 + jc)*4 + g)*8 + rb2];
    }

    // MFMA: all B from registers (both p slices per wave)
    i32x4 acc[2][4];
    #pragma unroll
    for (int p = 0; p < 2; ++p)
      #pragma unroll
      for (int g = 0; g < 4; ++g){
        acc[p][g] = (i32x4){0,0,0,0};
        #pragma unroll
        for (int kk = 0; kk < 4; ++kk)
          acc[p][g] = __builtin_amdgcn_mfma_i32_16x16x64_i8(a[kk], breg[p][g][kk], acc[p][g], 0, 0, 0);
      }

    // redistribute: lanes >=32 take p=1 gates from partner (lane-32)
    i32x4 accL[4];
    #pragma unroll
    for (int g = 0; g < 4; ++g)
      #pragma unroll
      for (int r = 0; r < 4; ++r){
        int tswp = __shfl_xor(acc[1][g][r], 32, 64);
        accL[g][r] = (lane < 32) ? acc[0][g][r] : tswp;
      }

    // MODE0: x rows for this lane
    float4 xr[4];
    if (MODE == 0){
      #pragma unroll
      for (int r = 0; r < 4; ++r)
        xr[r] = *(const float4*)&x_lds[tt & 1][rb2 + r][0];
    }

    // ---- elementwise: 4 cells/lane (col jc, rows rb2..rb2+3) ----
    float4 wvv[4]; float bb[4];
    if (MODE == 0){
      #pragma unroll
      for (int g = 0; g < 4; ++g){
        wvv[g] = wv_lds[g*256 + jc];
        bb[g]  = bia_lds[g*256 + jc];
      }
    }
    float hvf[4];
    #pragma unroll
    for (int r = 0; r < 4; ++r){
      float gv[4];
      if (MODE == 0){
        #pragma unroll
        for (int g = 0; g < 4; ++g){
          float t0 = fmaf(xr[r].x, wvv[g].x, bb[g]);
          t0 = fmaf(xr[r].y, wvv[g].y, t0);
          t0 = fmaf(xr[r].z, wvv[g].z, t0);
          t0 = fmaf(xr[r].w, wvv[g].w, t0);
          gv[g] = fmaf((float)accL[g][r], cmb_l[g], t0);
        }
      } else {
        #pragma unroll
        for (int g = 0; g < 4; ++g){
          unsigned uu = (r < 2) ? cinC[g].x : cinC[g].y;
          float ci = bf2f((unsigned short)((r & 1) ? (uu >> 16) : (uu & 0xFFFF)));
          gv[g] = fmaf((float)accL[g][r], cmb_l[g], ci);
        }
      }
      float cc = sigmf(gv[1])*c_reg[r] + sigmf(gv[0])*tanhf_(gv[2]);
      c_reg[r] = cc;
      float h = sigmf(gv[3])*tanhf_(cc);
      hvf[r] = h;
      int row = rb2 + r;
      float hcl = fminf(127.f, fmaxf(-127.f, h*127.f));
      An[(row << 8) + ((((jc >> 4) ^ row)) << 4) + (jc & 15)] = (char)__float2int_rn(hcl);
      if (MODE == 1 && tt == T_LEN-1)
        hS[(size_t)(b0r + row)*HID + jc] = h;
    }
    if (MODE == 0){
      // HW bf16 pack (RNE) + lane-pair shuffle -> u32 y0 stores
      unsigned pk0, pk1;
      asm("v_cvt_pk_bf16_f32 %0, %1, %2" : "=v"(pk0) : "v"(hvf[0]), "v"(hvf[1]));
      asm("v_cvt_pk_bf16_f32 %0, %1, %2" : "=v"(pk1) : "v"(hvf[2]), "v"(hvf[3]));
      unsigned nb0 = (unsigned)__shfl_xor((int)pk0, 1, 64);
      unsigned nb1 = (unsigned)__shfl_xor((int)pk1, 1, 64);
      unsigned s0v = odd ? ((nb1 & 0xFFFFu) | (pk1 << 16))
                         : ((pk0 & 0xFFFFu) | (nb0 << 16));
      unsigned s1v = odd ? ((nb1 >> 16) | (pk1 & 0xFFFF0000u))
                         : ((pk0 >> 16) | (nb0 & 0xFFFF0000u));
      int r0 = rb2 + (odd ? 2 : 0);
      int colu = jc & ~1;
      *(unsigned*)&y0[((size_t)t*BATCH + (b0r + r0    ))*(2*HID) + dir*HID + colu] = s0v;
      *(unsigned*)&y0[((size_t)t*BATCH + (b0r + r0 + 1))*(2*HID) + dir*HID + colu] = s1v;
    }

    if (MODE == 0 && tid < 32){   // stage x(next)
      int tn = dir ? (t > 0 ? t-1 : 0) : (t < T_LEN-1 ? t+1 : t);
      int row = tid >> 2, i = tid & 3;
      x_lds[(tt + 1) & 1][row][i] = x[((size_t)(b0r+row)*T_LEN + tn)*4 + i];
    }

    if (MODE == 1){
      #pragma unroll
      for (int g = 0; g < 4; ++g) cinC[g] = cinN[g];
    }
  }
}

// ---- bf16 MFMA GEMM: C[M][1024] = A[M][512] * B[1024][512]^T + bias ----
// PLAIN=0: frag-packed bf16 out [t][bg:16][jc:256][g:4][rr:8]; PLAIN=1: fp32 [M][1024]
template<int PLAIN>
__global__ __launch_bounds__(256) void k_gemm_bf(
    const unsigned short* __restrict__ A, const unsigned short* __restrict__ B,
    const float* __restrict__ bias, unsigned short* __restrict__ outF, float* __restrict__ outP)
{
  __shared__ __align__(16) unsigned short As[128*64];
  __shared__ __align__(16) unsigned short Bs[128*64];
  const int tid  = threadIdx.x;
  const int lane = tid & 63;
  const int w = tid >> 6, wm = w >> 1, wn = w & 1;
  const int t  = blockIdx.y;
  const int n0 = blockIdx.x * 128;

  f32x4 acc[4][4];
  #pragma unroll
  for (int i = 0; i < 4; ++i)
    #pragma unroll
    for (int jx = 0; jx < 4; ++jx) acc[i][jx] = (f32x4){0.f,0.f,0.f,0.f};

  const int sr = tid >> 3;
  const int sq = tid & 7;

  for (int k0 = 0; k0 < 512; k0 += 64){
    #pragma unroll
    for (int it = 0; it < 4; ++it){
      int r = sr + it*32;
      uint4 av = *(const uint4*)&A[((size_t)t*128 + r)*512 + k0 + sq*8];
      uint4 bv = *(const uint4*)&B[((size_t)(n0 + r))*512 + k0 + sq*8];
      *(uint4*)&As[r*64 + (sq ^ (r & 7))*8] = av;
      *(uint4*)&Bs[r*64 + (sq ^ (r & 7))*8] = bv;
    }
    __syncthreads();
    bf16x8 af[4][2], bfv[4][2];
    #pragma unroll
    for (int mt = 0; mt < 4; ++mt)
      #pragma unroll
      for (int kk = 0; kk < 2; ++kk){
        int row = wm*64 + mt*16 + (lane & 15);
        af[mt][kk] = *(const bf16x8*)&As[row*64 + ((kk*4 + (lane>>4)) ^ (row & 7))*8];
      }
    #pragma unroll
    for (int nl = 0; nl < 4; ++nl)
      #pragma unroll
      for (int kk = 0; kk < 2; ++kk){
        int row = wn*64 + nl*16 + (lane & 15);
        bfv[nl][kk] = *(const bf16x8*)&Bs[row*64 + ((kk*4 + (lane>>4)) ^ (row & 7))*8];
      }
    #pragma unroll
    for (int mt = 0; mt < 4; ++mt)
      #pragma unroll
      for (int nl = 0; nl < 4; ++nl){
        acc[mt][nl] = __builtin_amdgcn_mfma_f32_16x16x32_bf16(af[mt][0], bfv[nl][0], acc[mt][nl], 0,0,0);
        acc[mt][nl] = __builtin_amdgcn_mfma_f32_16x16x32_bf16(af[mt][1], bfv[nl][1], acc[mt][nl], 0,0,0);
      }
    __syncthreads();
  }

  #pragma unroll
  for (int mt = 0; mt < 4; ++mt){
    #pragma unroll
    for (int nl = 0; nl < 4; ++nl){
      int ng = n0 + wn*64 + nl*16 + (lane & 15);
      float bv = bias[ng];
      f32x4 v = acc[mt][nl];
      if (PLAIN){
        int mrow = wm*64 + mt*16 + (lane >> 4)*4;
        #pragma unroll
        for (int r = 0; r < 4; ++r)
          outP[((size_t)t*128 + mrow + r)*G4 + ng] = v[r] + bv;
      } else {
        int bbase = wm*64 + mt*16 + ((lane >> 4) << 2);  // batch row base (x4 aligned)
        int bg  = bbase >> 3;
        int rr0 = bbase & 7;                              // 0 or 4
        int jc_hid = ng & 255;
        int g  = ng >> 8;
        unsigned short hb[4];
        #pragma unroll
        for (int r = 0; r < 4; ++r) hb[r] = f2bf(v[r] + bv);
        *(uint2*)&outF[((((size_t)t*16 + bg)*256 + jc_hid)*4 + g)*8 + rr0] = *(uint2*)hb;
      }
    }
  }
}

// ---- final: layer-1 bwd single step + combine + out proj + softmax ----
__global__ __launch_bounds__(256) void k_final(const float* __restrict__ hS,
                                               const float* __restrict__ xp1b,
                                               const float* __restrict__ w_out,
                                               const float* __restrict__ b_out,
                                               float* __restrict__ out)
{
  const int b = blockIdx.x, j = threadIdx.x;
  float iv = xp1b[b*G4 + 0*HID + j];
  float gv = xp1b[b*G4 + 2*HID + j];
  float ov = xp1b[b*G4 + 3*HID + j];
  float c  = sigmf(iv)*tanhf_(gv);
  float hb = sigmf(ov)*tanhf_(c);
  float last = hS[b*HID + j] + hb;

  __shared__ float part[3][256];
  part[0][j] = last * w_out[0*HID + j];
  part[1][j] = last * w_out[1*HID + j];
  part[2][j] = last * w_out[2*HID + j];
  __syncthreads();
  for (int s = 128; s > 0; s >>= 1){
    if (j < s){
      part[0][j] += part[0][j+s];
      part[1][j] += part[1][j+s];
      part[2][j] += part[2][j+s];
    }
    __syncthreads();
  }
  if (j == 0){
    float l0 = part[0][0] + b_out[0];
    float l1 = part[1][0] + b_out[1];
    float l2 = part[2][0] + b_out[2];
    float m = fmaxf(l0, fmaxf(l1, l2));
    float e0 = __expf(l0-m), e1 = __expf(l1-m), e2 = __expf(l2-m);
    float s = e0 + e1 + e2;
    out[b*3+0] = e0/s; out[b*3+1] = e1/s; out[b*3+2] = e2/s;
  }
}

extern "C" void kernel_launch(void* const* d_in, const int* in_sizes, int n_in,
                              void* d_out, int out_size, void* d_ws, size_t ws_size,
                              hipStream_t stream) {
  const float* x     = (const float*)d_in[0];
  const float* w_ih0 = (const float*)d_in[1];
  const float* w_hh0 = (const float*)d_in[2];
  const float* b0p   = (const float*)d_in[3];
  const float* w_ih1 = (const float*)d_in[4];
  const float* w_hh1 = (const float*)d_in[5];
  const float* b1p   = (const float*)d_in[6];
  const float* w_out = (const float*)d_in[7];
  const float* b_out = (const float*)d_in[8];
  float* out = (float*)d_out;

  // workspace layout
  unsigned short* y0    = (unsigned short*)d_ws;                 // 33,554,432 u16
  unsigned short* xp1   = y0    + (size_t)T_LEN*BATCH*2*HID;     // 67,108,864 u16
  unsigned short* wih1p = xp1   + (size_t)T_LEN*BATCH*G4;        // 1,048,576 u16
  float*          comb  = (float*)(wih1p + 2*G4*2*HID);          // 3072 f32
  float*          s_inv = comb  + 3*1024;                        // 3072 f32
  float*          xp1b  = s_inv + 3*1024;                        // 131,072 f32
  float*          hS    = xp1b  + BATCH*G4;                      // 32,768 f32
  char*           wpi8  = (char*)(hS + BATCH*HID);               // 786,432 B

  // weight prep
  k_scales<<<12, 256, 0, stream>>>(w_hh0, w_hh1, comb, s_inv);
  k_pack_i8<<<3072, 256, 0, stream>>>(w_hh0, w_hh1, s_inv, wpi8);
  k_pack_wih1<<<4096, 256, 0, stream>>>(w_ih1, wih1p, 2*G4*2*HID);

  // layer 0, both directions: batch-8 blocks, no exchange
  k_rec8<0><<<32, 512, 0, stream>>>(x, wpi8, comb, w_ih0, b0p, nullptr, y0, nullptr);

  // layer-1 input projection (fwd dir), frag-packed bf16 out
  k_gemm_bf<0><<<dim3(8, 512), 256, 0, stream>>>(y0, wih1p, b1p, xp1, nullptr);

  // layer-1 backward first step gates: plain fp32
  k_gemm_bf<1><<<dim3(8, 1), 256, 0, stream>>>(y0 + (size_t)(T_LEN-1)*BATCH*2*HID,
                                               wih1p + (size_t)G4*2*HID, b1p + G4,
                                               nullptr, xp1b);

  // layer 1 forward recurrence: batch-8 blocks
  k_rec8<1><<<16, 512, 0, stream>>>(nullptr, wpi8, comb, nullptr, nullptr, xp1, nullptr, hS);

  k_final<<<BATCH, 256, 0, stream>>>(hS, xp1b, w_out, b_out, out);
}

// Round 12
// 1085.404 us; speedup vs baseline: 3.4261x; 1.5897x over previous
//
#include <hip/hip_runtime.h>

typedef __attribute__((ext_vector_type(8))) short bf16x8;
typedef __attribute__((ext_vector_type(4))) float f32x4;
typedef __attribute__((ext_vector_type(4))) int   i32x4;

#define T_LEN 512
#define BATCH 128
#define HID   256
#define G4    1024
#define WPI8_STRIDE 262144   // bytes per dir-layer: 64 tiles * 4 kk * 64 lanes * 16

__device__ __forceinline__ float sigmf(float x){
  return __builtin_amdgcn_rcpf(1.0f + __expf(-x));
}
__device__ __forceinline__ float tanhf_(float x){
  return 1.0f - 2.0f*__builtin_amdgcn_rcpf(1.0f + __expf(2.0f*x));
}
__device__ __forceinline__ unsigned short f2bf(float f){
  union{float f;unsigned u;} v; v.f=f;
  unsigned r = v.u + 0x7FFF + ((v.u>>16)&1);
  return (unsigned short)(r>>16);
}
__device__ __forceinline__ float bf2f(unsigned short b){
  union{unsigned u;float f;} v; v.u = ((unsigned)b)<<16; return v.f;
}

// ---- per-column scales for i8 quantization ----
__global__ void k_scales(const float* __restrict__ w_hh0, const float* __restrict__ w_hh1,
                         float* __restrict__ comb, float* __restrict__ s_inv){
  int idx = blockIdx.x*256 + threadIdx.x;
  if (idx >= 3*1024) return;
  int dl = idx >> 10, n = idx & 1023;
  const float* src = (dl < 2) ? (w_hh0 + ((size_t)dl*1024 + n)*256)
                              : (w_hh1 + (size_t)n*256);
  float m = 1e-20f;
  for (int k = 0; k < 256; k += 4){
    float4 v = *(const float4*)&src[k];
    m = fmaxf(m, fmaxf(fmaxf(fabsf(v.x), fabsf(v.y)), fmaxf(fabsf(v.z), fabsf(v.w))));
  }
  s_inv[idx] = 127.f / m;
  comb[idx]  = m / 16129.f;
}

// ---- pack w_hh into i8 B-fragment order (original n ordering) ----
__global__ void k_pack_i8(const float* __restrict__ w_hh0, const float* __restrict__ w_hh1,
                          const float* __restrict__ s_inv, char* __restrict__ wp){
  int idx = blockIdx.x*256 + threadIdx.x;
  if (idx >= 3*WPI8_STRIDE) return;
  int j    = idx & 15;
  int lane = (idx >> 4) & 63;
  int kk   = (idx >> 10) & 3;
  int tile = (idx >> 12) & 63;
  int dl   = idx >> 18;
  int g = tile & 3, s = tile >> 2;
  int n = g*256 + s*16 + (lane & 15);
  int k = kk*64 + ((lane >> 4) << 4) + j;
  const float* src = (dl < 2) ? (w_hh0 + ((size_t)dl*1024 + n)*256)
                              : (w_hh1 + (size_t)n*256);
  float v = src[k] * s_inv[dl*1024 + n];
  int q = (int)rintf(fminf(127.f, fmaxf(-127.f, v)));
  wp[idx] = (char)q;
}

// ---- pack w_ih1: dir0 rows COLUMN-PERMUTED (n' = (s*16+c)*4+g), dir1 identity ----
// also emit permuted dir0 bias b1perm[n'] = b1[n]
__global__ void k_pack_wih1(const float* __restrict__ w, const float* __restrict__ b1,
                            unsigned short* __restrict__ o, float* __restrict__ b1perm){
  int idx = blockIdx.x*256 + threadIdx.x;
  if (idx >= 2*1024*512) return;
  int d     = idx >> 19;
  int rem   = idx & ((1 << 19) - 1);
  int n_out = rem >> 9;
  int k     = rem & 511;
  int n_src = d ? n_out
                : ((n_out & 3)*256 + (n_out >> 6)*16 + ((n_out >> 2) & 15));
  o[idx] = f2bf(w[((size_t)(d*1024 + n_src))*512 + k]);
  if (idx < 1024){
    int ns = (idx & 3)*256 + (idx >> 6)*16 + ((idx >> 2) & 15);
    b1perm[idx] = b1[ns];
  }
}

// ---- batch-4 single-CU recurrence, i8 weights register-resident ----
// MODE 0: layer0, 64 blocks (dir x 32 bgrp). MODE 1: layer1 fwd, 32 blocks.
// 512 thr = 8 waves (2/SIMD). A-REPLICATION: h stored compact [4][256] i8;
// each lane's A-frag address replicates row (lane&15)>>2 -> MFMA computes each
// batch row 4x redundantly -> every lane holds its 2 cells' gates in
// acc[p][g][0]. NO redistribution shuffles, all 64 lanes do 2 cells each.
template<int MODE>
__global__ __launch_bounds__(512, 2) void k_rec4(
    const float* __restrict__ x,
    const char* __restrict__ wpack,
    const float* __restrict__ comb,
    const float* __restrict__ w_ih0,
    const float* __restrict__ b0,
    const unsigned short* __restrict__ xp,   // MODE1 gates, frag layout
    unsigned short* __restrict__ y0,
    float* __restrict__ hS)
{
  const int tid  = threadIdx.x;
  const int lane = tid & 63;
  const int w    = tid >> 6;            // 0..7
  int dir, bgrp, dl;
  if (MODE == 0){ dir = blockIdx.x >> 5; bgrp = blockIdx.x & 31; dl = dir; }
  else          { dir = 0; bgrp = blockIdx.x; dl = 2; }
  const int b0r = bgrp * 4;

  // h i8 compact: [buf][row:4][288B] (256 cols + pad; stride 288B keeps the
  // 16-address replicated b128 read <=2-way bank aliased = free)
  __shared__ __align__(16) char   A_lds[2][4*288];
  __shared__ __align__(16) float  x_lds[2][4][4];   // MODE0 x stage
  __shared__ __align__(16) float4 wv_lds[1024];     // MODE0 w_ih[dir]
  __shared__ float bia_lds[1024];                   // MODE0 bias[dir]

  // all w_hh weights into registers (128 AGPR/wave)
  const i32x4* wpb = (const i32x4*)(wpack + (size_t)dl*WPI8_STRIDE);
  i32x4 breg[2][4][4];
  #pragma unroll
  for (int p = 0; p < 2; ++p)
    #pragma unroll
    for (int g = 0; g < 4; ++g)
      #pragma unroll
      for (int kk = 0; kk < 4; ++kk)
        breg[p][g][kk] = wpb[(((((2*w+p)*4 + g)*4) + kk) << 6) + lane];

  const int c   = lane & 15;
  const int bl  = lane >> 4;            // this lane's batch row 0..3
  const int jc0 = (2*w)*16 + c;         // p=0 hidden col
  const int jc1 = jc0 + 16;             // p=1 hidden col

  float cmb_l[2][4];
  #pragma unroll
  for (int g = 0; g < 4; ++g){
    cmb_l[0][g] = comb[dl*1024 + g*256 + jc0];
    cmb_l[1][g] = comb[dl*1024 + g*256 + jc1];
  }

  for (int i = tid; i < 2*4*288; i += 512) ((char*)A_lds)[i] = 0;  // h(0)=0
  if (MODE == 0){
    for (int i = tid; i < 1024; i += 512){
      wv_lds[i]  = *(const float4*)&w_ih0[(size_t)(dir*1024 + i)*4];
      bia_lds[i] = b0[dir*1024 + i];
    }
    if (tid < 16){
      int row = tid >> 2, i = tid & 3;
      int t0 = dir ? (T_LEN-1) : 0;
      x_lds[0][row][i] = x[((size_t)(b0r+row)*T_LEN + t0)*4 + i];
    }
  }

  float c_reg[2] = {0.f, 0.f};

  // MODE1: double-buffered C-in gates (2 cells x 4 gates = 2 x uint2)
  uint2 cinC[2], cinN[2];
  if (MODE == 1){
    #pragma unroll
    for (int p = 0; p < 2; ++p)
      cinC[p] = *(const uint2*)&xp[((((size_t)0*32 + bgrp)*16 + (2*w+p))*64 + lane)*4];
  }

  for (int tt = 0; tt < T_LEN; ++tt){
    const int t = (MODE == 0 && dir) ? (T_LEN-1-tt) : tt;
    const char* Ac = A_lds[tt & 1];
    char* An = (char*)A_lds[(tt + 1) & 1];

    __syncthreads();   // h(tt)/x(tt) complete in Ac

    // A fragments with row replication: A[row] = h[row>>2]
    i32x4 a[4];
    #pragma unroll
    for (int kk = 0; kk < 4; ++kk)
      a[kk] = *(const i32x4*)&Ac[(c >> 2)*288 + kk*64 + ((lane >> 4) << 4)];

    if (MODE == 1){   // prefetch next step's gates
      int tn = (t + 1 < T_LEN) ? t + 1 : t;
      #pragma unroll
      for (int p = 0; p < 2; ++p)
        cinN[p] = *(const uint2*)&xp[((((size_t)tn*32 + bgrp)*16 + (2*w+p))*64 + lane)*4];
    }

    // MFMA: all B from registers
    i32x4 acc[2][4];
    #pragma unroll
    for (int p = 0; p < 2; ++p)
      #pragma unroll
      for (int g = 0; g < 4; ++g){
        acc[p][g] = (i32x4){0,0,0,0};
        #pragma unroll
        for (int kk = 0; kk < 4; ++kk)
          acc[p][g] = __builtin_amdgcn_mfma_i32_16x16x64_i8(a[kk], breg[p][g][kk], acc[p][g], 0, 0, 0);
      }

    float4 xr;
    if (MODE == 0) xr = *(const float4*)&x_lds[tt & 1][bl][0];

    // ---- elementwise: 2 cells/lane, gates in acc[p][g][0] (replicated) ----
    float hv[2];
    #pragma unroll
    for (int p = 0; p < 2; ++p){
      const int jc = p ? jc1 : jc0;
      float gv[4];
      if (MODE == 0){
        #pragma unroll
        for (int g = 0; g < 4; ++g){
          float4 wv4 = wv_lds[g*256 + jc];
          float t0 = fmaf(xr.x, wv4.x, bia_lds[g*256 + jc]);
          t0 = fmaf(xr.y, wv4.y, t0);
          t0 = fmaf(xr.z, wv4.z, t0);
          t0 = fmaf(xr.w, wv4.w, t0);
          gv[g] = fmaf((float)acc[p][g][0], cmb_l[p][g], t0);
        }
      } else {
        unsigned lo = cinC[p].x, hi = cinC[p].y;
        gv[0] = fmaf((float)acc[p][0][0], cmb_l[p][0], bf2f((unsigned short)(lo & 0xFFFF)));
        gv[1] = fmaf((float)acc[p][1][0], cmb_l[p][1], bf2f((unsigned short)(lo >> 16)));
        gv[2] = fmaf((float)acc[p][2][0], cmb_l[p][2], bf2f((unsigned short)(hi & 0xFFFF)));
        gv[3] = fmaf((float)acc[p][3][0], cmb_l[p][3], bf2f((unsigned short)(hi >> 16)));
      }
      float cc = sigmf(gv[1])*c_reg[p] + sigmf(gv[0])*tanhf_(gv[2]);
      c_reg[p] = cc;
      float h = sigmf(gv[3])*tanhf_(cc);
      hv[p] = h;
      float hcl = fminf(127.f, fmaxf(-127.f, h*127.f));
      An[bl*288 + jc] = (char)__float2int_rn(hcl);
      if (MODE == 1 && tt == T_LEN-1)
        hS[(size_t)(b0r + bl)*HID + jc] = h;
    }
    if (MODE == 0){
      unsigned pk;
      asm("v_cvt_pk_bf16_f32 %0, %1, %2" : "=v"(pk) : "v"(hv[0]), "v"(hv[1]));
      size_t yb = ((size_t)t*BATCH + (b0r + bl))*(2*HID) + dir*HID;
      y0[yb + jc0] = (unsigned short)(pk & 0xFFFFu);
      y0[yb + jc1] = (unsigned short)(pk >> 16);
    }

    if (MODE == 0 && tid < 16){   // stage x(next)
      int tn = dir ? (t > 0 ? t-1 : 0) : (t < T_LEN-1 ? t+1 : t);
      int row = tid >> 2, i = tid & 3;
      x_lds[(tt + 1) & 1][row][i] = x[((size_t)(b0r+row)*T_LEN + tn)*4 + i];
    }
    if (MODE == 1){ cinC[0] = cinN[0]; cinC[1] = cinN[1]; }
  }
}

// ---- bf16 MFMA GEMM: C[M][1024] = A[M][512] * B[1024][512]^T + bias ----
// PLAIN=0: B/bias are PERMUTED (n' order); writes xp frag layout
//   [t][bg:32][s:16][lane:64][g:4] bf16. PLAIN=1: plain fp32 [M][1024].
template<int PLAIN>
__global__ __launch_bounds__(256) void k_gemm_bf(
    const unsigned short* __restrict__ A, const unsigned short* __restrict__ B,
    const float* __restrict__ bias, unsigned short* __restrict__ outF, float* __restrict__ outP)
{
  __shared__ __align__(16) unsigned short As[128*64];
  __shared__ __align__(16) unsigned short Bs[128*64];
  const int tid  = threadIdx.x;
  const int lane = tid & 63;
  const int w = tid >> 6, wm = w >> 1, wn = w & 1;
  const int t  = blockIdx.y;
  const int n0 = blockIdx.x * 128;

  f32x4 acc[4][4];
  #pragma unroll
  for (int i = 0; i < 4; ++i)
    #pragma unroll
    for (int jx = 0; jx < 4; ++jx) acc[i][jx] = (f32x4){0.f,0.f,0.f,0.f};

  const int sr = tid >> 3;
  const int sq = tid & 7;

  for (int k0 = 0; k0 < 512; k0 += 64){
    #pragma unroll
    for (int it = 0; it < 4; ++it){
      int r = sr + it*32;
      uint4 av = *(const uint4*)&A[((size_t)t*128 + r)*512 + k0 + sq*8];
      uint4 bv = *(const uint4*)&B[((size_t)(n0 + r))*512 + k0 + sq*8];
      *(uint4*)&As[r*64 + (sq ^ (r & 7))*8] = av;
      *(uint4*)&Bs[r*64 + (sq ^ (r & 7))*8] = bv;
    }
    __syncthreads();
    bf16x8 af[4][2], bfv[4][2];
    #pragma unroll
    for (int mt = 0; mt < 4; ++mt)
      #pragma unroll
      for (int kk = 0; kk < 2; ++kk){
        int row = wm*64 + mt*16 + (lane & 15);
        af[mt][kk] = *(const bf16x8*)&As[row*64 + ((kk*4 + (lane>>4)) ^ (row & 7))*8];
      }
    #pragma unroll
    for (int nl = 0; nl < 4; ++nl)
      #pragma unroll
      for (int kk = 0; kk < 2; ++kk){
        int row = wn*64 + nl*16 + (lane & 15);
        bfv[nl][kk] = *(const bf16x8*)&Bs[row*64 + ((kk*4 + (lane>>4)) ^ (row & 7))*8];
      }
    #pragma unroll
    for (int mt = 0; mt < 4; ++mt)
      #pragma unroll
      for (int nl = 0; nl < 4; ++nl){
        acc[mt][nl] = __builtin_amdgcn_mfma_f32_16x16x32_bf16(af[mt][0], bfv[nl][0], acc[mt][nl], 0,0,0);
        acc[mt][nl] = __builtin_amdgcn_mfma_f32_16x16x32_bf16(af[mt][1], bfv[nl][1], acc[mt][nl], 0,0,0);
      }
    __syncthreads();
  }

  #pragma unroll
  for (int mt = 0; mt < 4; ++mt){
    #pragma unroll
    for (int nl = 0; nl < 4; ++nl){
      int ng = n0 + wn*64 + nl*16 + (lane & 15);
      float bv = bias[ng];
      f32x4 v = acc[mt][nl];
      if (PLAIN){
        int mrow = wm*64 + mt*16 + (lane >> 4)*4;
        #pragma unroll
        for (int r = 0; r < 4; ++r)
          outP[((size_t)t*128 + mrow + r)*G4 + ng] = v[r] + bv;
      } else {
        // ng is PERMUTED col n' = (s*16+c)*4 + g
        int g  = ng & 3;
        int cp = (ng >> 2) & 15;
        int s  = ng >> 6;
        int bbase = wm*64 + mt*16 + ((lane >> 4) << 2);
        int bg = bbase >> 2;
        size_t base = (((size_t)t*32 + bg)*16 + s)*256;
        #pragma unroll
        for (int r = 0; r < 4; ++r)
          outF[base + ((r*16 + cp) << 2) + g] = f2bf(v[r] + bv);
      }
    }
  }
}

// ---- final: layer-1 bwd single step + combine + out proj + softmax ----
__global__ __launch_bounds__(256) void k_final(const float* __restrict__ hS,
                                               const float* __restrict__ xp1b,
                                               const float* __restrict__ w_out,
                                               const float* __restrict__ b_out,
                                               float* __restrict__ out)
{
  const int b = blockIdx.x, j = threadIdx.x;
  float iv = xp1b[b*G4 + 0*HID + j];
  float gv = xp1b[b*G4 + 2*HID + j];
  float ov = xp1b[b*G4 + 3*HID + j];
  float c  = sigmf(iv)*tanhf_(gv);
  float hb = sigmf(ov)*tanhf_(c);
  float last = hS[b*HID + j] + hb;

  __shared__ float part[3][256];
  part[0][j] = last * w_out[0*HID + j];
  part[1][j] = last * w_out[1*HID + j];
  part[2][j] = last * w_out[2*HID + j];
  __syncthreads();
  for (int s = 128; s > 0; s >>= 1){
    if (j < s){
      part[0][j] += part[0][j+s];
      part[1][j] += part[1][j+s];
      part[2][j] += part[2][j+s];
    }
    __syncthreads();
  }
  if (j == 0){
    float l0 = part[0][0] + b_out[0];
    float l1 = part[1][0] + b_out[1];
    float l2 = part[2][0] + b_out[2];
    float m = fmaxf(l0, fmaxf(l1, l2));
    float e0 = __expf(l0-m), e1 = __expf(l1-m), e2 = __expf(l2-m);
    float s = e0 + e1 + e2;
    out[b*3+0] = e0/s; out[b*3+1] = e1/s; out[b*3+2] = e2/s;
  }
}

extern "C" void kernel_launch(void* const* d_in, const int* in_sizes, int n_in,
                              void* d_out, int out_size, void* d_ws, size_t ws_size,
                              hipStream_t stream) {
  const float* x     = (const float*)d_in[0];
  const float* w_ih0 = (const float*)d_in[1];
  const float* w_hh0 = (const float*)d_in[2];
  const float* b0p   = (const float*)d_in[3];
  const float* w_ih1 = (const float*)d_in[4];
  const float* w_hh1 = (const float*)d_in[5];
  const float* b1p   = (const float*)d_in[6];
  const float* w_out = (const float*)d_in[7];
  const float* b_out = (const float*)d_in[8];
  float* out = (float*)d_out;

  // workspace layout (u16 units unless noted)
  unsigned short* y0    = (unsigned short*)d_ws;                 // 33,554,432 u16
  unsigned short* xp1   = y0    + (size_t)T_LEN*BATCH*2*HID;     // 67,108,864 u16
  unsigned short* wih1p = xp1   + (size_t)T_LEN*BATCH*G4;        // 1,048,576 u16
  float*          comb  = (float*)(wih1p + 2*G4*2*HID);          // 3072 f32
  float*          s_inv = comb  + 3*1024;                        // 3072 f32
  float*          b1pm  = s_inv + 3*1024;                        // 1024 f32
  float*          xp1b  = b1pm  + 1024;                          // 131,072 f32
  float*          hS    = xp1b  + BATCH*G4;                      // 32,768 f32
  char*           wpi8  = (char*)(hS + BATCH*HID);               // 786,432 B

  // weight prep
  k_scales<<<12, 256, 0, stream>>>(w_hh0, w_hh1, comb, s_inv);
  k_pack_i8<<<3072, 256, 0, stream>>>(w_hh0, w_hh1, s_inv, wpi8);
  k_pack_wih1<<<4096, 256, 0, stream>>>(w_ih1, b1p, wih1p, b1pm);

  // layer 0, both directions: batch-4 blocks, A-replication
  k_rec4<0><<<64, 512, 0, stream>>>(x, wpi8, comb, w_ih0, b0p, nullptr, y0, nullptr);

  // layer-1 input projection (fwd dir), permuted-B frag-packed bf16 out
  k_gemm_bf<0><<<dim3(8, 512), 256, 0, stream>>>(y0, wih1p, b1pm, xp1, nullptr);

  // layer-1 backward first step gates: plain fp32 (dir1 B unpermuted)
  k_gemm_bf<1><<<dim3(8, 1), 256, 0, stream>>>(y0 + (size_t)(T_LEN-1)*BATCH*2*HID,
                                               wih1p + (size_t)G4*2*HID, b1p + G4,
                                               nullptr, xp1b);

  // layer 1 forward recurrence: batch-4 blocks
  k_rec4<1><<<32, 512, 0, stream>>>(nullptr, wpi8, comb, nullptr, nullptr, xp1, nullptr, hS);

  k_final<<<BATCH, 256, 0, stream>>>(hS, xp1b, w_out, b_out, out);
}

// Round 13
// 1003.665 us; speedup vs baseline: 3.7051x; 1.0814x over previous
//
#include <hip/hip_runtime.h>

typedef __attribute__((ext_vector_type(8))) short bf16x8;
typedef __attribute__((ext_vector_type(4))) float f32x4;
typedef __attribute__((ext_vector_type(4))) int   i32x4;

#define T_LEN 512
#define BATCH 128
#define HID   256
#define G4    1024
#define WPI8_STRIDE 262144   // bytes per dir-layer: 64 tiles * 4 kk * 64 lanes * 16

__device__ __forceinline__ float sigmf(float x){
  return __builtin_amdgcn_rcpf(1.0f + __expf(-x));
}
__device__ __forceinline__ float tanhf_(float x){
  return 1.0f - 2.0f*__builtin_amdgcn_rcpf(1.0f + __expf(2.0f*x));
}
__device__ __forceinline__ unsigned short f2bf(float f){
  union{float f;unsigned u;} v; v.f=f;
  unsigned r = v.u + 0x7FFF + ((v.u>>16)&1);
  return (unsigned short)(r>>16);
}
__device__ __forceinline__ float bf2f(unsigned short b){
  union{unsigned u;float f;} v; v.u = ((unsigned)b)<<16; return v.f;
}

// ---- per-column scales for i8 quantization ----
__global__ void k_scales(const float* __restrict__ w_hh0, const float* __restrict__ w_hh1,
                         float* __restrict__ comb, float* __restrict__ s_inv){
  int idx = blockIdx.x*256 + threadIdx.x;
  if (idx >= 3*1024) return;
  int dl = idx >> 10, n = idx & 1023;
  const float* src = (dl < 2) ? (w_hh0 + ((size_t)dl*1024 + n)*256)
                              : (w_hh1 + (size_t)n*256);
  float m = 1e-20f;
  for (int k = 0; k < 256; k += 4){
    float4 v = *(const float4*)&src[k];
    m = fmaxf(m, fmaxf(fmaxf(fabsf(v.x), fabsf(v.y)), fmaxf(fabsf(v.z), fabsf(v.w))));
  }
  s_inv[idx] = 127.f / m;
  comb[idx]  = m / 16129.f;
}

// ---- pack w_hh into i8 B-fragment order ----
__global__ void k_pack_i8(const float* __restrict__ w_hh0, const float* __restrict__ w_hh1,
                          const float* __restrict__ s_inv, char* __restrict__ wp){
  int idx = blockIdx.x*256 + threadIdx.x;
  if (idx >= 3*WPI8_STRIDE) return;
  int j    = idx & 15;
  int lane = (idx >> 4) & 63;
  int kk   = (idx >> 10) & 3;
  int tile = (idx >> 12) & 63;
  int dl   = idx >> 18;
  int g = tile & 3, s = tile >> 2;
  int n = g*256 + s*16 + (lane & 15);
  int k = kk*64 + ((lane >> 4) << 4) + j;
  const float* src = (dl < 2) ? (w_hh0 + ((size_t)dl*1024 + n)*256)
                              : (w_hh1 + (size_t)n*256);
  float v = src[k] * s_inv[dl*1024 + n];
  int q = (int)rintf(fminf(127.f, fmaxf(-127.f, v)));
  wp[idx] = (char)q;
}

// ---- pack w_ih1: dir0 rows COLUMN-PERMUTED (n' = (s*16+c)*4+g), dir1 identity ----
__global__ void k_pack_wih1(const float* __restrict__ w, const float* __restrict__ b1,
                            unsigned short* __restrict__ o, float* __restrict__ b1perm){
  int idx = blockIdx.x*256 + threadIdx.x;
  if (idx >= 2*1024*512) return;
  int d     = idx >> 19;
  int rem   = idx & ((1 << 19) - 1);
  int n_out = rem >> 9;
  int k     = rem & 511;
  int n_src = d ? n_out
                : ((n_out & 3)*256 + (n_out >> 6)*16 + ((n_out >> 2) & 15));
  o[idx] = f2bf(w[((size_t)(d*1024 + n_src))*512 + k]);
  if (idx < 1024){
    int ns = (idx & 3)*256 + (idx >> 6)*16 + ((idx >> 2) & 15);
    b1perm[idx] = b1[ns];
  }
}

// ---- batch-2 single-CU recurrence, i8 weights register-resident ----
// MODE 0: layer0, 128 blocks (dir x 64 bgrp). MODE 1: layer1 fwd, 64 blocks.
// 512 thr = 8 waves (2/SIMD). A-replication A[row]=h[row&1] -> D row m holds
// batch m&1 -> lane (bl=(lane>>4)&1, pl=lane>>5, c) owns ONE cell; gates
// extracted from acc[pl][g][bl] via cndmask selects (static indices only).
template<int MODE>
__global__ __launch_bounds__(512, 2) void k_rec2(
    const float* __restrict__ x,
    const char* __restrict__ wpack,
    const float* __restrict__ comb,
    const float* __restrict__ w_ih0,
    const float* __restrict__ b0,
    const unsigned short* __restrict__ xp,   // MODE1 gates, frag layout
    unsigned short* __restrict__ y0,
    float* __restrict__ hS)
{
  const int tid  = threadIdx.x;
  const int lane = tid & 63;
  const int w    = tid >> 6;            // 0..7
  int dir, bgrp, dl;
  if (MODE == 0){ dir = blockIdx.x >> 6; bgrp = blockIdx.x & 63; dl = dir; }
  else          { dir = 0; bgrp = blockIdx.x; dl = 2; }
  const int b0r = bgrp * 2;

  __shared__ __align__(16) char   A_lds[2][2*288];  // h i8 compact, 2 rows
  __shared__ __align__(16) float  x_lds[2][2][4];   // MODE0 x stage
  __shared__ __align__(16) float4 wv_lds[1024];     // MODE0 w_ih[dir]
  __shared__ float bia_lds[1024];                   // MODE0 bias[dir]

  // all w_hh weights into registers (128 AGPR/wave)
  const i32x4* wpb = (const i32x4*)(wpack + (size_t)dl*WPI8_STRIDE);
  i32x4 breg[2][4][4];
  #pragma unroll
  for (int p = 0; p < 2; ++p)
    #pragma unroll
    for (int g = 0; g < 4; ++g)
      #pragma unroll
      for (int kk = 0; kk < 4; ++kk)
        breg[p][g][kk] = wpb[(((((2*w+p)*4 + g)*4) + kk) << 6) + lane];

  const int c  = lane & 15;
  const int bl = (lane >> 4) & 1;       // this lane's batch row
  const int pl = lane >> 5;             // this lane's p slice
  const int jc = (2*w + pl)*16 + c;     // this lane's hidden col

  float cmb_l[4];
  #pragma unroll
  for (int g = 0; g < 4; ++g)
    cmb_l[g] = comb[dl*1024 + g*256 + jc];

  for (int i = tid; i < 2*2*288; i += 512) ((char*)A_lds)[i] = 0;  // h(0)=0
  if (MODE == 0){
    for (int i = tid; i < 1024; i += 512){
      wv_lds[i]  = *(const float4*)&w_ih0[(size_t)(dir*1024 + i)*4];
      bia_lds[i] = b0[dir*1024 + i];
    }
    if (tid < 8){
      int row = tid >> 2, i = tid & 3;
      int t0 = dir ? (T_LEN-1) : 0;
      x_lds[0][row][i] = x[((size_t)(b0r+row)*T_LEN + t0)*4 + i];
    }
  }

  float c_reg = 0.f;

  // MODE1: double-buffered C-in gates (1 cell x 4 gates = uint2)
  uint2 cinC, cinN;
  if (MODE == 1)
    cinC = *(const uint2*)&xp[((((size_t)0*64 + bgrp)*8 + w)*64 + lane)*4];

  for (int tt = 0; tt < T_LEN; ++tt){
    const int t = (MODE == 0 && dir) ? (T_LEN-1-tt) : tt;
    const char* Ac = A_lds[tt & 1];
    char* An = (char*)A_lds[(tt + 1) & 1];

    __syncthreads();   // h(tt)/x(tt) complete in Ac

    // A fragments, row-replicated: A[row] = h[row & 1]
    i32x4 a[4];
    #pragma unroll
    for (int kk = 0; kk < 4; ++kk)
      a[kk] = *(const i32x4*)&Ac[(c & 1)*288 + kk*64 + ((lane >> 4) << 4)];

    if (MODE == 1){   // prefetch next step's gates
      int tn = (t + 1 < T_LEN) ? t + 1 : t;
      cinN = *(const uint2*)&xp[((((size_t)tn*64 + bgrp)*8 + w)*64 + lane)*4];
    }

    // MFMA: all B from registers (both p slices; duplication is free on the
    // 43%-busy matrix pipe)
    i32x4 acc[2][4];
    #pragma unroll
    for (int p = 0; p < 2; ++p)
      #pragma unroll
      for (int g = 0; g < 4; ++g){
        acc[p][g] = (i32x4){0,0,0,0};
        #pragma unroll
        for (int kk = 0; kk < 4; ++kk)
          acc[p][g] = __builtin_amdgcn_mfma_i32_16x16x64_i8(a[kk], breg[p][g][kk], acc[p][g], 0, 0, 0);
      }

    float4 xr;
    if (MODE == 0) xr = *(const float4*)&x_lds[tt & 1][bl][0];

    // ---- elementwise: ONE cell per lane ----
    float gv[4];
    #pragma unroll
    for (int g = 0; g < 4; ++g){
      // static-index extracts + cndmask selects (no dynamic vector indexing)
      int a0 = bl ? acc[0][g][1] : acc[0][g][0];
      int a1 = bl ? acc[1][g][1] : acc[1][g][0];
      int ia = pl ? a1 : a0;
      if (MODE == 0){
        float4 wv4 = wv_lds[g*256 + jc];
        float t0 = fmaf(xr.x, wv4.x, bia_lds[g*256 + jc]);
        t0 = fmaf(xr.y, wv4.y, t0);
        t0 = fmaf(xr.z, wv4.z, t0);
        t0 = fmaf(xr.w, wv4.w, t0);
        gv[g] = fmaf((float)ia, cmb_l[g], t0);
      } else {
        unsigned uu = (g < 2) ? cinC.x : cinC.y;
        float ci = bf2f((unsigned short)((g & 1) ? (uu >> 16) : (uu & 0xFFFF)));
        gv[g] = fmaf((float)ia, cmb_l[g], ci);
      }
    }
    float cc = sigmf(gv[1])*c_reg + sigmf(gv[0])*tanhf_(gv[2]);
    c_reg = cc;
    float h = sigmf(gv[3])*tanhf_(cc);
    float hcl = fminf(127.f, fmaxf(-127.f, h*127.f));
    An[bl*288 + jc] = (char)__float2int_rn(hcl);

    if (MODE == 0){
      unsigned pk;
      asm("v_cvt_pk_bf16_f32 %0, %1, %2" : "=v"(pk) : "v"(h), "v"(h));
      y0[((size_t)t*BATCH + (b0r + bl))*(2*HID) + dir*HID + jc] = (unsigned short)pk;
    } else if (tt == T_LEN-1){
      hS[(size_t)(b0r + bl)*HID + jc] = h;
    }

    if (MODE == 0 && tid < 8){   // stage x(next)
      int tn = dir ? (t > 0 ? t-1 : 0) : (t < T_LEN-1 ? t+1 : t);
      int row = tid >> 2, i = tid & 3;
      x_lds[(tt + 1) & 1][row][i] = x[((size_t)(b0r+row)*T_LEN + tn)*4 + i];
    }
    if (MODE == 1) cinC = cinN;
  }
}

// ---- bf16 MFMA GEMM: C[M][1024] = A[M][512] * B[1024][512]^T + bias ----
// PLAIN=0: B/bias PERMUTED (n' = (s*16+c)*4+g); writes xp frag layout
//   [t][bg:64][w:8][lane:64][g:4] bf16. PLAIN=1: plain fp32 [M][1024].
template<int PLAIN>
__global__ __launch_bounds__(256) void k_gemm_bf(
    const unsigned short* __restrict__ A, const unsigned short* __restrict__ B,
    const float* __restrict__ bias, unsigned short* __restrict__ outF, float* __restrict__ outP)
{
  __shared__ __align__(16) unsigned short As[128*64];
  __shared__ __align__(16) unsigned short Bs[128*64];
  const int tid  = threadIdx.x;
  const int lane = tid & 63;
  const int w = tid >> 6, wm = w >> 1, wn = w & 1;
  const int t  = blockIdx.y;
  const int n0 = blockIdx.x * 128;

  f32x4 acc[4][4];
  #pragma unroll
  for (int i = 0; i < 4; ++i)
    #pragma unroll
    for (int jx = 0; jx < 4; ++jx) acc[i][jx] = (f32x4){0.f,0.f,0.f,0.f};

  const int sr = tid >> 3;
  const int sq = tid & 7;

  for (int k0 = 0; k0 < 512; k0 += 64){
    #pragma unroll
    for (int it = 0; it < 4; ++it){
      int r = sr + it*32;
      uint4 av = *(const uint4*)&A[((size_t)t*128 + r)*512 + k0 + sq*8];
      uint4 bv = *(const uint4*)&B[((size_t)(n0 + r))*512 + k0 + sq*8];
      *(uint4*)&As[r*64 + (sq ^ (r & 7))*8] = av;
      *(uint4*)&Bs[r*64 + (sq ^ (r & 7))*8] = bv;
    }
    __syncthreads();
    bf16x8 af[4][2], bfv[4][2];
    #pragma unroll
    for (int mt = 0; mt < 4; ++mt)
      #pragma unroll
      for (int kk = 0; kk < 2; ++kk){
        int row = wm*64 + mt*16 + (lane & 15);
        af[mt][kk] = *(const bf16x8*)&As[row*64 + ((kk*4 + (lane>>4)) ^ (row & 7))*8];
      }
    #pragma unroll
    for (int nl = 0; nl < 4; ++nl)
      #pragma unroll
      for (int kk = 0; kk < 2; ++kk){
        int row = wn*64 + nl*16 + (lane & 15);
        bfv[nl][kk] = *(const bf16x8*)&Bs[row*64 + ((kk*4 + (lane>>4)) ^ (row & 7))*8];
      }
    #pragma unroll
    for (int mt = 0; mt < 4; ++mt)
      #pragma unroll
      for (int nl = 0; nl < 4; ++nl){
        acc[mt][nl] = __builtin_amdgcn_mfma_f32_16x16x32_bf16(af[mt][0], bfv[nl][0], acc[mt][nl], 0,0,0);
        acc[mt][nl] = __builtin_amdgcn_mfma_f32_16x16x32_bf16(af[mt][1], bfv[nl][1], acc[mt][nl], 0,0,0);
      }
    __syncthreads();
  }

  #pragma unroll
  for (int mt = 0; mt < 4; ++mt){
    #pragma unroll
    for (int nl = 0; nl < 4; ++nl){
      int ng = n0 + wn*64 + nl*16 + (lane & 15);
      float bv = bias[ng];
      f32x4 v = acc[mt][nl];
      if (PLAIN){
        int mrow = wm*64 + mt*16 + (lane >> 4)*4;
        #pragma unroll
        for (int r = 0; r < 4; ++r)
          outP[((size_t)t*128 + mrow + r)*G4 + ng] = v[r] + bv;
      } else {
        // ng is PERMUTED col n' = (s*16+cc)*4 + g
        int g  = ng & 3;
        int cc = (ng >> 2) & 15;
        int s  = ng >> 6;
        int mrow = wm*64 + mt*16 + ((lane >> 4) << 2);
        #pragma unroll
        for (int r = 0; r < 4; ++r){
          int m  = mrow + r;
          int bg = m >> 1, bb = m & 1;
          outF[((((size_t)t*64 + bg)*8 + (s >> 1))*64
                + (((s & 1) << 5) | (bb << 4) | cc))*4 + g] = f2bf(v[r] + bv);
        }
      }
    }
  }
}

// ---- final: layer-1 bwd single step + combine + out proj + softmax ----
__global__ __launch_bounds__(256) void k_final(const float* __restrict__ hS,
                                               const float* __restrict__ xp1b,
                                               const float* __restrict__ w_out,
                                               const float* __restrict__ b_out,
                                               float* __restrict__ out)
{
  const int b = blockIdx.x, j = threadIdx.x;
  float iv = xp1b[b*G4 + 0*HID + j];
  float gv = xp1b[b*G4 + 2*HID + j];
  float ov = xp1b[b*G4 + 3*HID + j];
  float c  = sigmf(iv)*tanhf_(gv);
  float hb = sigmf(ov)*tanhf_(c);
  float last = hS[b*HID + j] + hb;

  __shared__ float part[3][256];
  part[0][j] = last * w_out[0*HID + j];
  part[1][j] = last * w_out[1*HID + j];
  part[2][j] = last * w_out[2*HID + j];
  __syncthreads();
  for (int s = 128; s > 0; s >>= 1){
    if (j < s){
      part[0][j] += part[0][j+s];
      part[1][j] += part[1][j+s];
      part[2][j] += part[2][j+s];
    }
    __syncthreads();
  }
  if (j == 0){
    float l0 = part[0][0] + b_out[0];
    float l1 = part[1][0] + b_out[1];
    float l2 = part[2][0] + b_out[2];
    float m = fmaxf(l0, fmaxf(l1, l2));
    float e0 = __expf(l0-m), e1 = __expf(l1-m), e2 = __expf(l2-m);
    float s = e0 + e1 + e2;
    out[b*3+0] = e0/s; out[b*3+1] = e1/s; out[b*3+2] = e2/s;
  }
}

extern "C" void kernel_launch(void* const* d_in, const int* in_sizes, int n_in,
                              void* d_out, int out_size, void* d_ws, size_t ws_size,
                              hipStream_t stream) {
  const float* x     = (const float*)d_in[0];
  const float* w_ih0 = (const float*)d_in[1];
  const float* w_hh0 = (const float*)d_in[2];
  const float* b0p   = (const float*)d_in[3];
  const float* w_ih1 = (const float*)d_in[4];
  const float* w_hh1 = (const float*)d_in[5];
  const float* b1p   = (const float*)d_in[6];
  const float* w_out = (const float*)d_in[7];
  const float* b_out = (const float*)d_in[8];
  float* out = (float*)d_out;

  // workspace layout (u16 units unless noted)
  unsigned short* y0    = (unsigned short*)d_ws;                 // 33,554,432 u16
  unsigned short* xp1   = y0    + (size_t)T_LEN*BATCH*2*HID;     // 67,108,864 u16
  unsigned short* wih1p = xp1   + (size_t)T_LEN*BATCH*G4;        // 1,048,576 u16
  float*          comb  = (float*)(wih1p + 2*G4*2*HID);          // 3072 f32
  float*          s_inv = comb  + 3*1024;                        // 3072 f32
  float*          b1pm  = s_inv + 3*1024;                        // 1024 f32
  float*          xp1b  = b1pm  + 1024;                          // 131,072 f32
  float*          hS    = xp1b  + BATCH*G4;                      // 32,768 f32
  char*           wpi8  = (char*)(hS + BATCH*HID);               // 786,432 B

  // weight prep
  k_scales<<<12, 256, 0, stream>>>(w_hh0, w_hh1, comb, s_inv);
  k_pack_i8<<<3072, 256, 0, stream>>>(w_hh0, w_hh1, s_inv, wpi8);
  k_pack_wih1<<<4096, 256, 0, stream>>>(w_ih1, b1p, wih1p, b1pm);

  // layer 0, both directions: batch-2 blocks, A-replication x2
  k_rec2<0><<<128, 512, 0, stream>>>(x, wpi8, comb, w_ih0, b0p, nullptr, y0, nullptr);

  // layer-1 input projection (fwd dir), permuted-B frag-packed bf16 out
  k_gemm_bf<0><<<dim3(8, 512), 256, 0, stream>>>(y0, wih1p, b1pm, xp1, nullptr);

  // layer-1 backward first step gates: plain fp32 (dir1 B unpermuted)
  k_gemm_bf<1><<<dim3(8, 1), 256, 0, stream>>>(y0 + (size_t)(T_LEN-1)*BATCH*2*HID,
                                               wih1p + (size_t)G4*2*HID, b1p + G4,
                                               nullptr, xp1b);

  // layer 1 forward recurrence: batch-2 blocks
  k_rec2<1><<<64, 512, 0, stream>>>(nullptr, wpi8, comb, nullptr, nullptr, xp1, nullptr, hS);

  k_final<<<BATCH, 256, 0, stream>>>(hS, xp1b, w_out, b_out, out);
}

// Round 14
// 994.346 us; speedup vs baseline: 3.7399x; 1.0094x over previous
//
#include <hip/hip_runtime.h>

typedef __attribute__((ext_vector_type(8))) short bf16x8;
typedef __attribute__((ext_vector_type(4))) float f32x4;
typedef __attribute__((ext_vector_type(4))) int   i32x4;

#define T_LEN 512
#define BATCH 128
#define HID   256
#define G4    1024
#define WPI8_STRIDE 262144   // bytes per dir-layer: 64 tiles * 4 kk * 64 lanes * 16
#define L2E   1.4426950408889634f

__device__ __forceinline__ float sigmf(float x){
  return __builtin_amdgcn_rcpf(1.0f + __expf(-x));
}
__device__ __forceinline__ float tanhf_(float x){
  return 1.0f - 2.0f*__builtin_amdgcn_rcpf(1.0f + __expf(2.0f*x));
}
// pre-folded variants: input already scaled by log2e (sig) / 2*log2e (tanh)
__device__ __forceinline__ float sig2(float y){
  return __builtin_amdgcn_rcpf(1.0f + __builtin_amdgcn_exp2f(-y));
}
__device__ __forceinline__ float tanh2(float y){
  return 1.0f - 2.0f*__builtin_amdgcn_rcpf(1.0f + __builtin_amdgcn_exp2f(y));
}
__device__ __forceinline__ unsigned short f2bf(float f){
  union{float f;unsigned u;} v; v.f=f;
  unsigned r = v.u + 0x7FFF + ((v.u>>16)&1);
  return (unsigned short)(r>>16);
}
__device__ __forceinline__ float bf2f(unsigned short b){
  union{unsigned u;float f;} v; v.u = ((unsigned)b)<<16; return v.f;
}

// ---- per-column scales for i8 quantization ----
__global__ void k_scales(const float* __restrict__ w_hh0, const float* __restrict__ w_hh1,
                         float* __restrict__ comb, float* __restrict__ s_inv){
  int idx = blockIdx.x*256 + threadIdx.x;
  if (idx >= 3*1024) return;
  int dl = idx >> 10, n = idx & 1023;
  const float* src = (dl < 2) ? (w_hh0 + ((size_t)dl*1024 + n)*256)
                              : (w_hh1 + (size_t)n*256);
  float m = 1e-20f;
  for (int k = 0; k < 256; k += 4){
    float4 v = *(const float4*)&src[k];
    m = fmaxf(m, fmaxf(fmaxf(fabsf(v.x), fabsf(v.y)), fmaxf(fabsf(v.z), fabsf(v.w))));
  }
  s_inv[idx] = 127.f / m;
  comb[idx]  = m / 16129.f;
}

// ---- pack w_hh into i8 B-fragment order ----
__global__ void k_pack_i8(const float* __restrict__ w_hh0, const float* __restrict__ w_hh1,
                          const float* __restrict__ s_inv, char* __restrict__ wp){
  int idx = blockIdx.x*256 + threadIdx.x;
  if (idx >= 3*WPI8_STRIDE) return;
  int j    = idx & 15;
  int lane = (idx >> 4) & 63;
  int kk   = (idx >> 10) & 3;
  int tile = (idx >> 12) & 63;
  int dl   = idx >> 18;
  int g = tile & 3, s = tile >> 2;
  int n = g*256 + s*16 + (lane & 15);
  int k = kk*64 + ((lane >> 4) << 4) + j;
  const float* src = (dl < 2) ? (w_hh0 + ((size_t)dl*1024 + n)*256)
                              : (w_hh1 + (size_t)n*256);
  float v = src[k] * s_inv[dl*1024 + n];
  int q = (int)rintf(fminf(127.f, fmaxf(-127.f, v)));
  wp[idx] = (char)q;
}

// ---- pack w_ih1: dir0 rows COLUMN-PERMUTED (n' = (s*16+c)*4+g), dir1 identity ----
__global__ void k_pack_wih1(const float* __restrict__ w, const float* __restrict__ b1,
                            unsigned short* __restrict__ o, float* __restrict__ b1perm){
  int idx = blockIdx.x*256 + threadIdx.x;
  if (idx >= 2*1024*512) return;
  int d     = idx >> 19;
  int rem   = idx & ((1 << 19) - 1);
  int n_out = rem >> 9;
  int k     = rem & 511;
  int n_src = d ? n_out
                : ((n_out & 3)*256 + (n_out >> 6)*16 + ((n_out >> 2) & 15));
  o[idx] = f2bf(w[((size_t)(d*1024 + n_src))*512 + k]);
  if (idx < 1024){
    int ns = (idx & 3)*256 + (idx >> 6)*16 + ((idx >> 2) & 15);
    b1perm[idx] = b1[ns];
  }
}

// ---- batch-2 single-CU recurrence, i8 weights register-resident ----
// Round-14: step-invariant w_ih/bias hoisted from per-step LDS broadcast reads
// (8 x ~100cy serial latency, the measured rec0-rec1 gap) into 20 registers;
// gate pre-activations pre-scaled by log2e (2*log2e for tanh gate) so the
// transcendental chain uses raw exp2 (no input muls).
template<int MODE>
__global__ __launch_bounds__(512, 2) void k_rec2(
    const float* __restrict__ x,
    const char* __restrict__ wpack,
    const float* __restrict__ comb,
    const float* __restrict__ w_ih0,
    const float* __restrict__ b0,
    const unsigned short* __restrict__ xp,   // MODE1 gates, frag layout, PRE-FOLDED
    unsigned short* __restrict__ y0,
    float* __restrict__ hS)
{
  const int tid  = threadIdx.x;
  const int lane = tid & 63;
  const int w    = tid >> 6;            // 0..7
  int dir, bgrp, dl;
  if (MODE == 0){ dir = blockIdx.x >> 6; bgrp = blockIdx.x & 63; dl = dir; }
  else          { dir = 0; bgrp = blockIdx.x; dl = 2; }
  const int b0r = bgrp * 2;

  __shared__ __align__(16) char   A_lds[2][2*288];  // h i8 compact, 2 rows
  __shared__ __align__(16) float  x_lds[2][2][4];   // MODE0 x stage

  // all w_hh weights into registers (128 AGPR/wave)
  const i32x4* wpb = (const i32x4*)(wpack + (size_t)dl*WPI8_STRIDE);
  i32x4 breg[2][4][4];
  #pragma unroll
  for (int p = 0; p < 2; ++p)
    #pragma unroll
    for (int g = 0; g < 4; ++g)
      #pragma unroll
      for (int kk = 0; kk < 4; ++kk)
        breg[p][g][kk] = wpb[(((((2*w+p)*4 + g)*4) + kk) << 6) + lane];

  const int c  = lane & 15;
  const int bl = (lane >> 4) & 1;       // this lane's batch row
  const int pl = lane >> 5;             // this lane's p slice
  const int jc = (2*w + pl)*16 + c;     // this lane's hidden col

  const float FOLD[4] = {L2E, L2E, 2.f*L2E, L2E};

  float cmb_l[4];
  #pragma unroll
  for (int g = 0; g < 4; ++g)
    cmb_l[g] = comb[dl*1024 + g*256 + jc] * FOLD[g];

  // MODE0: step-invariant w_ih slice + bias in REGISTERS (20 regs), pre-folded
  float4 wvr[4]; float biar[4];
  if (MODE == 0){
    #pragma unroll
    for (int g = 0; g < 4; ++g){
      float4 wv4 = *(const float4*)&w_ih0[(size_t)(dir*1024 + g*256 + jc)*4];
      wv4.x *= FOLD[g]; wv4.y *= FOLD[g]; wv4.z *= FOLD[g]; wv4.w *= FOLD[g];
      wvr[g]  = wv4;
      biar[g] = b0[dir*1024 + g*256 + jc] * FOLD[g];
    }
  }

  for (int i = tid; i < 2*2*288; i += 512) ((char*)A_lds)[i] = 0;  // h(0)=0
  if (MODE == 0 && tid < 8){
    int row = tid >> 2, i = tid & 3;
    int t0 = dir ? (T_LEN-1) : 0;
    x_lds[0][row][i] = x[((size_t)(b0r+row)*T_LEN + t0)*4 + i];
  }

  float c_reg = 0.f;

  // MODE1: double-buffered C-in gates (1 cell x 4 gates = uint2)
  uint2 cinC, cinN;
  if (MODE == 1)
    cinC = *(const uint2*)&xp[((((size_t)0*64 + bgrp)*8 + w)*64 + lane)*4];

  for (int tt = 0; tt < T_LEN; ++tt){
    const int t = (MODE == 0 && dir) ? (T_LEN-1-tt) : tt;
    const char* Ac = A_lds[tt & 1];
    char* An = (char*)A_lds[(tt + 1) & 1];

    __syncthreads();   // h(tt)/x(tt) complete in Ac

    // A fragments, row-replicated: A[row] = h[row & 1]
    i32x4 a[4];
    #pragma unroll
    for (int kk = 0; kk < 4; ++kk)
      a[kk] = *(const i32x4*)&Ac[(c & 1)*288 + kk*64 + ((lane >> 4) << 4)];

    if (MODE == 1){   // prefetch next step's gates
      int tn = (t + 1 < T_LEN) ? t + 1 : t;
      cinN = *(const uint2*)&xp[((((size_t)tn*64 + bgrp)*8 + w)*64 + lane)*4];
    }

    // MFMA: all B from registers
    i32x4 acc[2][4];
    #pragma unroll
    for (int p = 0; p < 2; ++p)
      #pragma unroll
      for (int g = 0; g < 4; ++g){
        acc[p][g] = (i32x4){0,0,0,0};
        #pragma unroll
        for (int kk = 0; kk < 4; ++kk)
          acc[p][g] = __builtin_amdgcn_mfma_i32_16x16x64_i8(a[kk], breg[p][g][kk], acc[p][g], 0, 0, 0);
      }

    float4 xr;
    if (MODE == 0) xr = *(const float4*)&x_lds[tt & 1][bl][0];

    // ---- elementwise: ONE cell per lane, all operands in registers ----
    float gv[4];
    #pragma unroll
    for (int g = 0; g < 4; ++g){
      int a0 = bl ? acc[0][g][1] : acc[0][g][0];
      int a1 = bl ? acc[1][g][1] : acc[1][g][0];
      int ia = pl ? a1 : a0;
      if (MODE == 0){
        float t0 = fmaf(xr.x, wvr[g].x, biar[g]);
        t0 = fmaf(xr.y, wvr[g].y, t0);
        t0 = fmaf(xr.z, wvr[g].z, t0);
        t0 = fmaf(xr.w, wvr[g].w, t0);
        gv[g] = fmaf((float)ia, cmb_l[g], t0);
      } else {
        unsigned uu = (g < 2) ? cinC.x : cinC.y;
        float ci = bf2f((unsigned short)((g & 1) ? (uu >> 16) : (uu & 0xFFFF)));
        gv[g] = fmaf((float)ia, cmb_l[g], ci);
      }
    }
    float cc = sig2(gv[1])*c_reg + sig2(gv[0])*tanh2(gv[2]);
    c_reg = cc;
    float h = sig2(gv[3])*tanhf_(cc);
    float hcl = fminf(127.f, fmaxf(-127.f, h*127.f));
    An[bl*288 + jc] = (char)__float2int_rn(hcl);

    if (MODE == 0){
      unsigned pk;
      asm("v_cvt_pk_bf16_f32 %0, %1, %2" : "=v"(pk) : "v"(h), "v"(h));
      y0[((size_t)t*BATCH + (b0r + bl))*(2*HID) + dir*HID + jc] = (unsigned short)pk;
    } else if (tt == T_LEN-1){
      hS[(size_t)(b0r + bl)*HID + jc] = h;
    }

    if (MODE == 0 && tid < 8){   // stage x(next)
      int tn = dir ? (t > 0 ? t-1 : 0) : (t < T_LEN-1 ? t+1 : t);
      int row = tid >> 2, i = tid & 3;
      x_lds[(tt + 1) & 1][row][i] = x[((size_t)(b0r+row)*T_LEN + tn)*4 + i];
    }
    if (MODE == 1) cinC = cinN;
  }
}

// ---- bf16 MFMA GEMM: C[M][1024] = A[M][512] * B[1024][512]^T + bias ----
// PLAIN=0: B/bias PERMUTED (n' = (s*16+c)*4+g); writes xp frag layout
//   [t][bg:64][w:8][lane:64][g:4] bf16, values PRE-FOLDED by per-gate log2e.
// PLAIN=1: plain fp32 [M][1024], unfolded.
template<int PLAIN>
__global__ __launch_bounds__(256) void k_gemm_bf(
    const unsigned short* __restrict__ A, const unsigned short* __restrict__ B,
    const float* __restrict__ bias, unsigned short* __restrict__ outF, float* __restrict__ outP)
{
  __shared__ __align__(16) unsigned short As[128*64];
  __shared__ __align__(16) unsigned short Bs[128*64];
  const int tid  = threadIdx.x;
  const int lane = tid & 63;
  const int w = tid >> 6, wm = w >> 1, wn = w & 1;
  const int t  = blockIdx.y;
  const int n0 = blockIdx.x * 128;

  f32x4 acc[4][4];
  #pragma unroll
  for (int i = 0; i < 4; ++i)
    #pragma unroll
    for (int jx = 0; jx < 4; ++jx) acc[i][jx] = (f32x4){0.f,0.f,0.f,0.f};

  const int sr = tid >> 3;
  const int sq = tid & 7;

  for (int k0 = 0; k0 < 512; k0 += 64){
    #pragma unroll
    for (int it = 0; it < 4; ++it){
      int r = sr + it*32;
      uint4 av = *(const uint4*)&A[((size_t)t*128 + r)*512 + k0 + sq*8];
      uint4 bv = *(const uint4*)&B[((size_t)(n0 + r))*512 + k0 + sq*8];
      *(uint4*)&As[r*64 + (sq ^ (r & 7))*8] = av;
      *(uint4*)&Bs[r*64 + (sq ^ (r & 7))*8] = bv;
    }
    __syncthreads();
    bf16x8 af[4][2], bfv[4][2];
    #pragma unroll
    for (int mt = 0; mt < 4; ++mt)
      #pragma unroll
      for (int kk = 0; kk < 2; ++kk){
        int row = wm*64 + mt*16 + (lane & 15);
        af[mt][kk] = *(const bf16x8*)&As[row*64 + ((kk*4 + (lane>>4)) ^ (row & 7))*8];
      }
    #pragma unroll
    for (int nl = 0; nl < 4; ++nl)
      #pragma unroll
      for (int kk = 0; kk < 2; ++kk){
        int row = wn*64 + nl*16 + (lane & 15);
        bfv[nl][kk] = *(const bf16x8*)&Bs[row*64 + ((kk*4 + (lane>>4)) ^ (row & 7))*8];
      }
    #pragma unroll
    for (int mt = 0; mt < 4; ++mt)
      #pragma unroll
      for (int nl = 0; nl < 4; ++nl){
        acc[mt][nl] = __builtin_amdgcn_mfma_f32_16x16x32_bf16(af[mt][0], bfv[nl][0], acc[mt][nl], 0,0,0);
        acc[mt][nl] = __builtin_amdgcn_mfma_f32_16x16x32_bf16(af[mt][1], bfv[nl][1], acc[mt][nl], 0,0,0);
      }
    __syncthreads();
  }

  #pragma unroll
  for (int mt = 0; mt < 4; ++mt){
    #pragma unroll
    for (int nl = 0; nl < 4; ++nl){
      int ng = n0 + wn*64 + nl*16 + (lane & 15);
      float bv = bias[ng];
      f32x4 v = acc[mt][nl];
      if (PLAIN){
        int mrow = wm*64 + mt*16 + (lane >> 4)*4;
        #pragma unroll
        for (int r = 0; r < 4; ++r)
          outP[((size_t)t*128 + mrow + r)*G4 + ng] = v[r] + bv;
      } else {
        // ng is PERMUTED col n' = (s*16+cc)*4 + g; pre-fold by gate
        int g  = ng & 3;
        int cc = (ng >> 2) & 15;
        int s  = ng >> 6;
        float fold = (g == 2) ? (2.f*L2E) : L2E;
        int mrow = wm*64 + mt*16 + ((lane >> 4) << 2);
        #pragma unroll
        for (int r = 0; r < 4; ++r){
          int m  = mrow + r;
          int bg = m >> 1, bb = m & 1;
          outF[((((size_t)t*64 + bg)*8 + (s >> 1))*64
                + (((s & 1) << 5) | (bb << 4) | cc))*4 + g] = f2bf((v[r] + bv)*fold);
        }
      }
    }
  }
}

// ---- final: layer-1 bwd single step + combine + out proj + softmax ----
__global__ __launch_bounds__(256) void k_final(const float* __restrict__ hS,
                                               const float* __restrict__ xp1b,
                                               const float* __restrict__ w_out,
                                               const float* __restrict__ b_out,
                                               float* __restrict__ out)
{
  const int b = blockIdx.x, j = threadIdx.x;
  float iv = xp1b[b*G4 + 0*HID + j];
  float gv = xp1b[b*G4 + 2*HID + j];
  float ov = xp1b[b*G4 + 3*HID + j];
  float c  = sigmf(iv)*tanhf_(gv);
  float hb = sigmf(ov)*tanhf_(c);
  float last = hS[b*HID + j] + hb;

  __shared__ float part[3][256];
  part[0][j] = last * w_out[0*HID + j];
  part[1][j] = last * w_out[1*HID + j];
  part[2][j] = last * w_out[2*HID + j];
  __syncthreads();
  for (int s = 128; s > 0; s >>= 1){
    if (j < s){
      part[0][j] += part[0][j+s];
      part[1][j] += part[1][j+s];
      part[2][j] += part[2][j+s];
    }
    __syncthreads();
  }
  if (j == 0){
    float l0 = part[0][0] + b_out[0];
    float l1 = part[1][0] + b_out[1];
    float l2 = part[2][0] + b_out[2];
    float m = fmaxf(l0, fmaxf(l1, l2));
    float e0 = __expf(l0-m), e1 = __expf(l1-m), e2 = __expf(l2-m);
    float s = e0 + e1 + e2;
    out[b*3+0] = e0/s; out[b*3+1] = e1/s; out[b*3+2] = e2/s;
  }
}

extern "C" void kernel_launch(void* const* d_in, const int* in_sizes, int n_in,
                              void* d_out, int out_size, void* d_ws, size_t ws_size,
                              hipStream_t stream) {
  const float* x     = (const float*)d_in[0];
  const float* w_ih0 = (const float*)d_in[1];
  const float* w_hh0 = (const float*)d_in[2];
  const float* b0p   = (const float*)d_in[3];
  const float* w_ih1 = (const float*)d_in[4];
  const float* w_hh1 = (const float*)d_in[5];
  const float* b1p   = (const float*)d_in[6];
  const float* w_out = (const float*)d_in[7];
  const float* b_out = (const float*)d_in[8];
  float* out = (float*)d_out;

  // workspace layout (u16 units unless noted)
  unsigned short* y0    = (unsigned short*)d_ws;                 // 33,554,432 u16
  unsigned short* xp1   = y0    + (size_t)T_LEN*BATCH*2*HID;     // 67,108,864 u16
  unsigned short* wih1p = xp1   + (size_t)T_LEN*BATCH*G4;        // 1,048,576 u16
  float*          comb  = (float*)(wih1p + 2*G4*2*HID);          // 3072 f32
  float*          s_inv = comb  + 3*1024;                        // 3072 f32
  float*          b1pm  = s_inv + 3*1024;                        // 1024 f32
  float*          xp1b  = b1pm  + 1024;                          // 131,072 f32
  float*          hS    = xp1b  + BATCH*G4;                      // 32,768 f32
  char*           wpi8  = (char*)(hS + BATCH*HID);               // 786,432 B

  // weight prep
  k_scales<<<12, 256, 0, stream>>>(w_hh0, w_hh1, comb, s_inv);
  k_pack_i8<<<3072, 256, 0, stream>>>(w_hh0, w_hh1, s_inv, wpi8);
  k_pack_wih1<<<4096, 256, 0, stream>>>(w_ih1, b1p, wih1p, b1pm);

  // layer 0, both directions: batch-2 blocks, A-replication x2
  k_rec2<0><<<128, 512, 0, stream>>>(x, wpi8, comb, w_ih0, b0p, nullptr, y0, nullptr);

  // layer-1 input projection (fwd dir), permuted-B frag-packed bf16 out (pre-folded)
  k_gemm_bf<0><<<dim3(8, 512), 256, 0, stream>>>(y0, wih1p, b1pm, xp1, nullptr);

  // layer-1 backward first step gates: plain fp32 (dir1 B unpermuted, unfolded)
  k_gemm_bf<1><<<dim3(8, 1), 256, 0, stream>>>(y0 + (size_t)(T_LEN-1)*BATCH*2*HID,
                                               wih1p + (size_t)G4*2*HID, b1p + G4,
                                               nullptr, xp1b);

  // layer 1 forward recurrence: batch-2 blocks
  k_rec2<1><<<64, 512, 0, stream>>>(nullptr, wpi8, comb, nullptr, nullptr, xp1, nullptr, hS);

  k_final<<<BATCH, 256, 0, stream>>>(hS, xp1b, w_out, b_out, out);
}

// Round 15
// 984.240 us; speedup vs baseline: 3.7783x; 1.0103x over previous
//
#include <hip/hip_runtime.h>

typedef __attribute__((ext_vector_type(8))) short bf16x8;
typedef __attribute__((ext_vector_type(4))) float f32x4;
typedef __attribute__((ext_vector_type(4))) int   i32x4;

#define T_LEN 512
#define BATCH 128
#define HID   256
#define G4    1024
#define WPI8_STRIDE 262144   // bytes per dir-layer
#define L2E   1.4426950408889634f

__device__ __forceinline__ float sigmf(float x){
  return __builtin_amdgcn_rcpf(1.0f + __expf(-x));
}
__device__ __forceinline__ float tanhf_(float x){
  return 1.0f - 2.0f*__builtin_amdgcn_rcpf(1.0f + __expf(2.0f*x));
}
__device__ __forceinline__ float sig2(float y){
  return __builtin_amdgcn_rcpf(1.0f + __builtin_amdgcn_exp2f(-y));
}
__device__ __forceinline__ float tanh2(float y){
  return 1.0f - 2.0f*__builtin_amdgcn_rcpf(1.0f + __builtin_amdgcn_exp2f(y));
}
__device__ __forceinline__ unsigned short f2bf(float f){
  union{float f;unsigned u;} v; v.f=f;
  unsigned r = v.u + 0x7FFF + ((v.u>>16)&1);
  return (unsigned short)(r>>16);
}
__device__ __forceinline__ float bf2f(unsigned short b){
  union{unsigned u;float f;} v; v.u = ((unsigned)b)<<16; return v.f;
}

// ---- per-column scales for i8 quantization ----
__global__ void k_scales(const float* __restrict__ w_hh0, const float* __restrict__ w_hh1,
                         float* __restrict__ comb, float* __restrict__ s_inv){
  int idx = blockIdx.x*256 + threadIdx.x;
  if (idx >= 3*1024) return;
  int dl = idx >> 10, n = idx & 1023;
  const float* src = (dl < 2) ? (w_hh0 + ((size_t)dl*1024 + n)*256)
                              : (w_hh1 + (size_t)n*256);
  float m = 1e-20f;
  for (int k = 0; k < 256; k += 4){
    float4 v = *(const float4*)&src[k];
    m = fmaxf(m, fmaxf(fmaxf(fabsf(v.x), fabsf(v.y)), fmaxf(fabsf(v.z), fabsf(v.w))));
  }
  s_inv[idx] = 127.f / m;
  comb[idx]  = m / 16129.f;
}

// ---- pack w_hh into i8 B-fragment order ----
__global__ void k_pack_i8(const float* __restrict__ w_hh0, const float* __restrict__ w_hh1,
                          const float* __restrict__ s_inv, char* __restrict__ wp){
  int idx = blockIdx.x*256 + threadIdx.x;
  if (idx >= 3*WPI8_STRIDE) return;
  int j    = idx & 15;
  int lane = (idx >> 4) & 63;
  int kk   = (idx >> 10) & 3;
  int tile = (idx >> 12) & 63;
  int dl   = idx >> 18;
  int g = tile & 3, s = tile >> 2;
  int n = g*256 + s*16 + (lane & 15);
  int k = kk*64 + ((lane >> 4) << 4) + j;
  const float* src = (dl < 2) ? (w_hh0 + ((size_t)dl*1024 + n)*256)
                              : (w_hh1 + (size_t)n*256);
  float v = src[k] * s_inv[dl*1024 + n];
  int q = (int)rintf(fminf(127.f, fmaxf(-127.f, v)));
  wp[idx] = (char)q;
}

// ---- pack w_ih1: dir0 rows COLUMN-PERMUTED (n' = (s*16+c)*4+g), dir1 identity ----
__global__ void k_pack_wih1(const float* __restrict__ w, const float* __restrict__ b1,
                            unsigned short* __restrict__ o, float* __restrict__ b1perm){
  int idx = blockIdx.x*256 + threadIdx.x;
  if (idx >= 2*1024*512) return;
  int d     = idx >> 19;
  int rem   = idx & ((1 << 19) - 1);
  int n_out = rem >> 9;
  int k     = rem & 511;
  int n_src = d ? n_out
                : ((n_out & 3)*256 + (n_out >> 6)*16 + ((n_out >> 2) & 15));
  o[idx] = f2bf(w[((size_t)(d*1024 + n_src))*512 + k]);
  if (idx < 1024){
    int ns = (idx & 3)*256 + (idx >> 6)*16 + ((idx >> 2) & 15);
    b1perm[idx] = b1[ns];
  }
}

// ---- layer-0 batch-2 recurrence (unchanged from round 14) ----
__global__ __launch_bounds__(512, 2) void k_rec0(
    const float* __restrict__ x,
    const char* __restrict__ wpack,
    const float* __restrict__ comb,
    const float* __restrict__ w_ih0,
    const float* __restrict__ b0,
    unsigned short* __restrict__ y0)
{
  const int tid  = threadIdx.x;
  const int lane = tid & 63;
  const int w    = tid >> 6;
  const int dir  = blockIdx.x >> 6;
  const int bgrp = blockIdx.x & 63;
  const int dl   = dir;
  const int b0r  = bgrp * 2;

  __shared__ __align__(16) char  A_lds[2][2*288];
  __shared__ __align__(16) float x_lds[2][2][4];

  const i32x4* wpb = (const i32x4*)(wpack + (size_t)dl*WPI8_STRIDE);
  i32x4 breg[2][4][4];
  #pragma unroll
  for (int p = 0; p < 2; ++p)
    #pragma unroll
    for (int g = 0; g < 4; ++g)
      #pragma unroll
      for (int kk = 0; kk < 4; ++kk)
        breg[p][g][kk] = wpb[(((((2*w+p)*4 + g)*4) + kk) << 6) + lane];

  const int c  = lane & 15;
  const int bl = (lane >> 4) & 1;
  const int pl = lane >> 5;
  const int jc = (2*w + pl)*16 + c;

  const float FOLD[4] = {L2E, L2E, 2.f*L2E, L2E};
  float cmb_l[4];
  #pragma unroll
  for (int g = 0; g < 4; ++g)
    cmb_l[g] = comb[dl*1024 + g*256 + jc] * FOLD[g];

  float4 wvr[4]; float biar[4];
  #pragma unroll
  for (int g = 0; g < 4; ++g){
    float4 wv4 = *(const float4*)&w_ih0[(size_t)(dir*1024 + g*256 + jc)*4];
    wv4.x *= FOLD[g]; wv4.y *= FOLD[g]; wv4.z *= FOLD[g]; wv4.w *= FOLD[g];
    wvr[g]  = wv4;
    biar[g] = b0[dir*1024 + g*256 + jc] * FOLD[g];
  }

  for (int i = tid; i < 2*2*288; i += 512) ((char*)A_lds)[i] = 0;
  if (tid < 8){
    int row = tid >> 2, i = tid & 3;
    int t0 = dir ? (T_LEN-1) : 0;
    x_lds[0][row][i] = x[((size_t)(b0r+row)*T_LEN + t0)*4 + i];
  }

  float c_reg = 0.f;

  for (int tt = 0; tt < T_LEN; ++tt){
    const int t = dir ? (T_LEN-1-tt) : tt;
    const char* Ac = A_lds[tt & 1];
    char* An = (char*)A_lds[(tt + 1) & 1];

    __syncthreads();

    i32x4 a[4];
    #pragma unroll
    for (int kk = 0; kk < 4; ++kk)
      a[kk] = *(const i32x4*)&Ac[(c & 1)*288 + kk*64 + ((lane >> 4) << 4)];

    i32x4 acc[2][4];
    #pragma unroll
    for (int p = 0; p < 2; ++p)
      #pragma unroll
      for (int g = 0; g < 4; ++g){
        acc[p][g] = (i32x4){0,0,0,0};
        #pragma unroll
        for (int kk = 0; kk < 4; ++kk)
          acc[p][g] = __builtin_amdgcn_mfma_i32_16x16x64_i8(a[kk], breg[p][g][kk], acc[p][g], 0, 0, 0);
      }

    float4 xr = *(const float4*)&x_lds[tt & 1][bl][0];

    float gv[4];
    #pragma unroll
    for (int g = 0; g < 4; ++g){
      int a0 = bl ? acc[0][g][1] : acc[0][g][0];
      int a1 = bl ? acc[1][g][1] : acc[1][g][0];
      int ia = pl ? a1 : a0;
      float t0 = fmaf(xr.x, wvr[g].x, biar[g]);
      t0 = fmaf(xr.y, wvr[g].y, t0);
      t0 = fmaf(xr.z, wvr[g].z, t0);
      t0 = fmaf(xr.w, wvr[g].w, t0);
      gv[g] = fmaf((float)ia, cmb_l[g], t0);
    }
    float cc = sig2(gv[1])*c_reg + sig2(gv[0])*tanh2(gv[2]);
    c_reg = cc;
    float h = sig2(gv[3])*tanhf_(cc);
    float hcl = fminf(127.f, fmaxf(-127.f, h*127.f));
    An[bl*288 + jc] = (char)__float2int_rn(hcl);

    unsigned pk;
    asm("v_cvt_pk_bf16_f32 %0, %1, %2" : "=v"(pk) : "v"(h), "v"(h));
    y0[((size_t)t*BATCH + (b0r + bl))*(2*HID) + dir*HID + jc] = (unsigned short)pk;

    if (tid < 8){
      int tn = dir ? (t > 0 ? t-1 : 0) : (t < T_LEN-1 ? t+1 : t);
      int row = tid >> 2, i = tid & 3;
      x_lds[(tt + 1) & 1][row][i] = x[((size_t)(b0r+row)*T_LEN + tn)*4 + i];
    }
  }
}

// ---- FUSED: xp1 GEMM producers (blocks 0-127) + layer-1 recurrence (128-191) ----
// Producers: 2x256-thr sub-gemms/block, chunk-major (8 chunks of 64 t),
// vmcnt(0)+barrier+agent-release cnt[c]. Consumers: poll cnt[c]>=512 (acquire)
// once per 64 steps before prefetching into a new chunk.
__global__ __launch_bounds__(512, 2) void k_l1_fused(
    const unsigned short* __restrict__ y0,
    const unsigned short* __restrict__ B,     // wih1p dir0, permuted
    const float* __restrict__ bias,           // b1pm (permuted)
    unsigned short* __restrict__ xp,          // frag layout, pre-folded
    const char* __restrict__ wpack,
    const float* __restrict__ comb,
    float* __restrict__ hS,
    unsigned* __restrict__ cnt)               // [8]
{
  __shared__ __align__(16) unsigned short As[2][128*64];
  __shared__ __align__(16) unsigned short Bs[2][128*64];
  __shared__ __align__(16) char A_lds[2][2*288];

  const int bx = blockIdx.x;

  if (bx < 128){
    // ------------- GEMM producer -------------
    const int tid5 = threadIdx.x;
    const int sub  = tid5 >> 8;
    const int tid  = tid5 & 255;
    const int lane = tid & 63;
    const int w = tid >> 6, wm = w >> 1, wn = w & 1;
    const int sr = tid >> 3, sq = tid & 7;
    const int worker = bx*2 + sub;

    for (int cch = 0; cch < 8; ++cch){
      for (int j = worker; j < 512; j += 256){
        const int t  = cch*64 + (j >> 3);
        const int n0 = (j & 7) * 128;

        f32x4 acc[4][4];
        #pragma unroll
        for (int i = 0; i < 4; ++i)
          #pragma unroll
          for (int jx = 0; jx < 4; ++jx) acc[i][jx] = (f32x4){0.f,0.f,0.f,0.f};

        for (int k0 = 0; k0 < 512; k0 += 64){
          #pragma unroll
          for (int it = 0; it < 4; ++it){
            int r = sr + it*32;
            uint4 av = *(const uint4*)&y0[((size_t)t*128 + r)*512 + k0 + sq*8];
            uint4 bv = *(const uint4*)&B[((size_t)(n0 + r))*512 + k0 + sq*8];
            *(uint4*)&As[sub][r*64 + (sq ^ (r & 7))*8] = av;
            *(uint4*)&Bs[sub][r*64 + (sq ^ (r & 7))*8] = bv;
          }
          __syncthreads();
          bf16x8 af[4][2], bfv[4][2];
          #pragma unroll
          for (int mt = 0; mt < 4; ++mt)
            #pragma unroll
            for (int kk = 0; kk < 2; ++kk){
              int row = wm*64 + mt*16 + (lane & 15);
              af[mt][kk] = *(const bf16x8*)&As[sub][row*64 + ((kk*4 + (lane>>4)) ^ (row & 7))*8];
            }
          #pragma unroll
          for (int nl = 0; nl < 4; ++nl)
            #pragma unroll
            for (int kk = 0; kk < 2; ++kk){
              int row = wn*64 + nl*16 + (lane & 15);
              bfv[nl][kk] = *(const bf16x8*)&Bs[sub][row*64 + ((kk*4 + (lane>>4)) ^ (row & 7))*8];
            }
          #pragma unroll
          for (int mt = 0; mt < 4; ++mt)
            #pragma unroll
            for (int nl = 0; nl < 4; ++nl){
              acc[mt][nl] = __builtin_amdgcn_mfma_f32_16x16x32_bf16(af[mt][0], bfv[nl][0], acc[mt][nl], 0,0,0);
              acc[mt][nl] = __builtin_amdgcn_mfma_f32_16x16x32_bf16(af[mt][1], bfv[nl][1], acc[mt][nl], 0,0,0);
            }
          __syncthreads();
        }

        #pragma unroll
        for (int mt = 0; mt < 4; ++mt){
          #pragma unroll
          for (int nl = 0; nl < 4; ++nl){
            int ng = n0 + wn*64 + nl*16 + (lane & 15);
            float bv = bias[ng];
            f32x4 v = acc[mt][nl];
            int g   = ng & 3;
            int ccx = (ng >> 2) & 15;
            int s   = ng >> 6;
            float fold = (g == 2) ? (2.f*L2E) : L2E;
            int mrow = wm*64 + mt*16 + ((lane >> 4) << 2);
            #pragma unroll
            for (int r = 0; r < 4; ++r){
              int m  = mrow + r;
              int bg = m >> 1, bb = m & 1;
              xp[((((size_t)t*64 + bg)*8 + (s >> 1))*64
                  + (((s & 1) << 5) | (bb << 4) | ccx))*4 + g] = f2bf((v[r] + bv)*fold);
            }
          }
        }
      }
      asm volatile("s_waitcnt vmcnt(0)" ::: "memory");
      __syncthreads();
      if (tid == 0)
        __hip_atomic_fetch_add(&cnt[cch], 2u, __ATOMIC_RELEASE, __HIP_MEMORY_SCOPE_AGENT);
    }
    return;
  }

  // ------------- layer-1 recurrence consumer -------------
  const int tid  = threadIdx.x;
  const int lane = tid & 63;
  const int w    = tid >> 6;
  const int bgrp = bx - 128;
  const int b0r  = bgrp * 2;

  const i32x4* wpb = (const i32x4*)(wpack + (size_t)2*WPI8_STRIDE);
  i32x4 breg[2][4][4];
  #pragma unroll
  for (int p = 0; p < 2; ++p)
    #pragma unroll
    for (int g = 0; g < 4; ++g)
      #pragma unroll
      for (int kk = 0; kk < 4; ++kk)
        breg[p][g][kk] = wpb[(((((2*w+p)*4 + g)*4) + kk) << 6) + lane];

  const int c  = lane & 15;
  const int bl = (lane >> 4) & 1;
  const int pl = lane >> 5;
  const int jc = (2*w + pl)*16 + c;

  const float FOLD[4] = {L2E, L2E, 2.f*L2E, L2E};
  float cmb_l[4];
  #pragma unroll
  for (int g = 0; g < 4; ++g)
    cmb_l[g] = comb[2*1024 + g*256 + jc] * FOLD[g];

  for (int i = tid; i < 2*2*288; i += 512) ((char*)A_lds)[i] = 0;

  float c_reg = 0.f;

  // wait for chunk 0 (xp[t=0..63]) before first cin load
  if (tid == 0)
    while (__hip_atomic_load(&cnt[0], __ATOMIC_ACQUIRE, __HIP_MEMORY_SCOPE_AGENT) < 512u) {}
  __syncthreads();

  uint2 cinC, cinN;
  cinC = *(const uint2*)&xp[((((size_t)0*64 + bgrp)*8 + w)*64 + lane)*4];

  for (int tt = 0; tt < T_LEN; ++tt){
    const int t = tt;
    const char* Ac = A_lds[tt & 1];
    char* An = (char*)A_lds[(tt + 1) & 1];

    // entering a new chunk next step? wait for its producer flag first
    if (tid == 0 && tt < T_LEN-1 && (tt & 63) == 63){
      int cn = (tt + 1) >> 6;
      while (__hip_atomic_load(&cnt[cn], __ATOMIC_ACQUIRE, __HIP_MEMORY_SCOPE_AGENT) < 512u) {}
    }
    __syncthreads();

    i32x4 a[4];
    #pragma unroll
    for (int kk = 0; kk < 4; ++kk)
      a[kk] = *(const i32x4*)&Ac[(c & 1)*288 + kk*64 + ((lane >> 4) << 4)];

    {
      int tn = (t + 1 < T_LEN) ? t + 1 : t;
      cinN = *(const uint2*)&xp[((((size_t)tn*64 + bgrp)*8 + w)*64 + lane)*4];
    }

    i32x4 acc[2][4];
    #pragma unroll
    for (int p = 0; p < 2; ++p)
      #pragma unroll
      for (int g = 0; g < 4; ++g){
        acc[p][g] = (i32x4){0,0,0,0};
        #pragma unroll
        for (int kk = 0; kk < 4; ++kk)
          acc[p][g] = __builtin_amdgcn_mfma_i32_16x16x64_i8(a[kk], breg[p][g][kk], acc[p][g], 0, 0, 0);
      }

    float gv[4];
    #pragma unroll
    for (int g = 0; g < 4; ++g){
      int a0 = bl ? acc[0][g][1] : acc[0][g][0];
      int a1 = bl ? acc[1][g][1] : acc[1][g][0];
      int ia = pl ? a1 : a0;
      unsigned uu = (g < 2) ? cinC.x : cinC.y;
      float ci = bf2f((unsigned short)((g & 1) ? (uu >> 16) : (uu & 0xFFFF)));
      gv[g] = fmaf((float)ia, cmb_l[g], ci);
    }
    float cc = sig2(gv[1])*c_reg + sig2(gv[0])*tanh2(gv[2]);
    c_reg = cc;
    float h = sig2(gv[3])*tanhf_(cc);
    float hcl = fminf(127.f, fmaxf(-127.f, h*127.f));
    An[bl*288 + jc] = (char)__float2int_rn(hcl);

    if (tt == T_LEN-1)
      hS[(size_t)(b0r + bl)*HID + jc] = h;

    cinC = cinN;
  }
}

// ---- plain bf16 GEMM for the single layer-1-backward step (fp32 out) ----
__global__ __launch_bounds__(256) void k_gemm_plain(
    const unsigned short* __restrict__ A, const unsigned short* __restrict__ B,
    const float* __restrict__ bias, float* __restrict__ outP)
{
  __shared__ __align__(16) unsigned short As[128*64];
  __shared__ __align__(16) unsigned short Bs[128*64];
  const int tid  = threadIdx.x;
  const int lane = tid & 63;
  const int w = tid >> 6, wm = w >> 1, wn = w & 1;
  const int t  = blockIdx.y;
  const int n0 = blockIdx.x * 128;

  f32x4 acc[4][4];
  #pragma unroll
  for (int i = 0; i < 4; ++i)
    #pragma unroll
    for (int jx = 0; jx < 4; ++jx) acc[i][jx] = (f32x4){0.f,0.f,0.f,0.f};

  const int sr = tid >> 3;
  const int sq = tid & 7;

  for (int k0 = 0; k0 < 512; k0 += 64){
    #pragma unroll
    for (int it = 0; it < 4; ++it){
      int r = sr + it*32;
      uint4 av = *(const uint4*)&A[((size_t)t*128 + r)*512 + k0 + sq*8];
      uint4 bv = *(const uint4*)&B[((size_t)(n0 + r))*512 + k0 + sq*8];
      *(uint4*)&As[r*64 + (sq ^ (r & 7))*8] = av;
      *(uint4*)&Bs[r*64 + (sq ^ (r & 7))*8] = bv;
    }
    __syncthreads();
    bf16x8 af[4][2], bfv[4][2];
    #pragma unroll
    for (int mt = 0; mt < 4; ++mt)
      #pragma unroll
      for (int kk = 0; kk < 2; ++kk){
        int row = wm*64 + mt*16 + (lane & 15);
        af[mt][kk] = *(const bf16x8*)&As[row*64 + ((kk*4 + (lane>>4)) ^ (row & 7))*8];
      }
    #pragma unroll
    for (int nl = 0; nl < 4; ++nl)
      #pragma unroll
      for (int kk = 0; kk < 2; ++kk){
        int row = wn*64 + nl*16 + (lane & 15);
        bfv[nl][kk] = *(const bf16x8*)&Bs[row*64 + ((kk*4 + (lane>>4)) ^ (row & 7))*8];
      }
    #pragma unroll
    for (int mt = 0; mt < 4; ++mt)
      #pragma unroll
      for (int nl = 0; nl < 4; ++nl){
        acc[mt][nl] = __builtin_amdgcn_mfma_f32_16x16x32_bf16(af[mt][0], bfv[nl][0], acc[mt][nl], 0,0,0);
        acc[mt][nl] = __builtin_amdgcn_mfma_f32_16x16x32_bf16(af[mt][1], bfv[nl][1], acc[mt][nl], 0,0,0);
      }
    __syncthreads();
  }

  #pragma unroll
  for (int mt = 0; mt < 4; ++mt){
    #pragma unroll
    for (int nl = 0; nl < 4; ++nl){
      int ng = n0 + wn*64 + nl*16 + (lane & 15);
      float bv = bias[ng];
      f32x4 v = acc[mt][nl];
      int mrow = wm*64 + mt*16 + (lane >> 4)*4;
      #pragma unroll
      for (int r = 0; r < 4; ++r)
        outP[((size_t)t*128 + mrow + r)*G4 + ng] = v[r] + bv;
    }
  }
}

// ---- final: layer-1 bwd single step + combine + out proj + softmax ----
__global__ __launch_bounds__(256) void k_final(const float* __restrict__ hS,
                                               const float* __restrict__ xp1b,
                                               const float* __restrict__ w_out,
                                               const float* __restrict__ b_out,
                                               float* __restrict__ out)
{
  const int b = blockIdx.x, j = threadIdx.x;
  float iv = xp1b[b*G4 + 0*HID + j];
  float gv = xp1b[b*G4 + 2*HID + j];
  float ov = xp1b[b*G4 + 3*HID + j];
  float c  = sigmf(iv)*tanhf_(gv);
  float hb = sigmf(ov)*tanhf_(c);
  float last = hS[b*HID + j] + hb;

  __shared__ float part[3][256];
  part[0][j] = last * w_out[0*HID + j];
  part[1][j] = last * w_out[1*HID + j];
  part[2][j] = last * w_out[2*HID + j];
  __syncthreads();
  for (int s = 128; s > 0; s >>= 1){
    if (j < s){
      part[0][j] += part[0][j+s];
      part[1][j] += part[1][j+s];
      part[2][j] += part[2][j+s];
    }
    __syncthreads();
  }
  if (j == 0){
    float l0 = part[0][0] + b_out[0];
    float l1 = part[1][0] + b_out[1];
    float l2 = part[2][0] + b_out[2];
    float m = fmaxf(l0, fmaxf(l1, l2));
    float e0 = __expf(l0-m), e1 = __expf(l1-m), e2 = __expf(l2-m);
    float s = e0 + e1 + e2;
    out[b*3+0] = e0/s; out[b*3+1] = e1/s; out[b*3+2] = e2/s;
  }
}

extern "C" void kernel_launch(void* const* d_in, const int* in_sizes, int n_in,
                              void* d_out, int out_size, void* d_ws, size_t ws_size,
                              hipStream_t stream) {
  const float* x     = (const float*)d_in[0];
  const float* w_ih0 = (const float*)d_in[1];
  const float* w_hh0 = (const float*)d_in[2];
  const float* b0p   = (const float*)d_in[3];
  const float* w_ih1 = (const float*)d_in[4];
  const float* w_hh1 = (const float*)d_in[5];
  const float* b1p   = (const float*)d_in[6];
  const float* w_out = (const float*)d_in[7];
  const float* b_out = (const float*)d_in[8];
  float* out = (float*)d_out;

  // workspace layout (u16 units unless noted)
  unsigned short* y0    = (unsigned short*)d_ws;                 // 33,554,432 u16
  unsigned short* xp1   = y0    + (size_t)T_LEN*BATCH*2*HID;     // 67,108,864 u16
  unsigned short* wih1p = xp1   + (size_t)T_LEN*BATCH*G4;        // 1,048,576 u16
  float*          comb  = (float*)(wih1p + 2*G4*2*HID);          // 3072 f32
  float*          s_inv = comb  + 3*1024;                        // 3072 f32
  float*          b1pm  = s_inv + 3*1024;                        // 1024 f32
  float*          xp1b  = b1pm  + 1024;                          // 131,072 f32
  float*          hS    = xp1b  + BATCH*G4;                      // 32,768 f32
  char*           wpi8  = (char*)(hS + BATCH*HID);               // 786,432 B
  unsigned*       cnt   = (unsigned*)(wpi8 + 3*WPI8_STRIDE);     // 8 u32

  // weight prep
  k_scales<<<12, 256, 0, stream>>>(w_hh0, w_hh1, comb, s_inv);
  k_pack_i8<<<3072, 256, 0, stream>>>(w_hh0, w_hh1, s_inv, wpi8);
  k_pack_wih1<<<4096, 256, 0, stream>>>(w_ih1, b1p, wih1p, b1pm);

  // layer 0, both directions: batch-2 blocks
  k_rec0<<<128, 512, 0, stream>>>(x, wpi8, comb, w_ih0, b0p, y0);

  // layer-1 backward first step gates: plain fp32 (dir1 B unpermuted)
  k_gemm_plain<<<dim3(8, 1), 256, 0, stream>>>(y0 + (size_t)(T_LEN-1)*BATCH*2*HID,
                                               wih1p + (size_t)G4*2*HID, b1p + G4, xp1b);

  // fused: xp1 producers + layer-1 forward recurrence consumers
  hipMemsetAsync(cnt, 0, 8*sizeof(unsigned), stream);
  k_l1_fused<<<192, 512, 0, stream>>>(y0, wih1p, b1pm, xp1, wpi8, comb, hS, cnt);

  k_final<<<BATCH, 256, 0, stream>>>(hS, xp1b, w_out, b_out, out);
}